// Round 1
// baseline (667.392 us; speedup 1.0000x reference)
//
#include <hip/hip_runtime.h>
#include <hip/hip_bf16.h>
#include <math.h>

#define B_    64
#define NKV   1024
#define NQ    8
#define S_    256
#define D_    256
#define H_    4
#define HD    64
#define HM    512
#define EPS_  1e-8f
#define LNEPS 1e-5f

// -------- helpers --------
__device__ __forceinline__ float wred_sum(float v) {
#pragma unroll
    for (int off = 32; off > 0; off >>= 1) v += __shfl_xor(v, off);
    return v;
}

// -------- 1. per-row mean/rstd of inputs (LN stats) --------
// grid 16384 x 256: one wave per row
__global__ __launch_bounds__(256) void rowstats_kernel(const float* __restrict__ in,
                                                       float* __restrict__ meanb,
                                                       float* __restrict__ rstdb) {
    int row  = blockIdx.x * 4 + (threadIdx.x >> 6);
    int lane = threadIdx.x & 63;
    float4 v = *(const float4*)(in + (size_t)row * 256 + lane * 4);
    float s1 = v.x + v.y + v.z + v.w;
    float s2 = v.x * v.x + v.y * v.y + v.z * v.z + v.w * v.w;
    s1 = wred_sum(s1);
    s2 = wred_sum(s2);
    if (lane == 0) {
        float m = s1 * (1.0f / 256.0f);
        float e2 = s2 * (1.0f / 256.0f);
        meanb[row] = m;
        rstdb[row] = rsqrtf(e2 - m * m + LNEPS);
    }
}

// -------- 2. KV projection: kv[row][0:256]=LN(x)@Wk*0.125, [256:512]=LN(x)@Wv --------
// 64x64 tile, BK=32, 256 threads, 4x4 per thread. grid (1024, 8)
__global__ __launch_bounds__(256) void kvproj_kernel(const float* __restrict__ in,
                                                     const float* __restrict__ meanb,
                                                     const float* __restrict__ rstdb,
                                                     const float* __restrict__ g,
                                                     const float* __restrict__ bb,
                                                     const float* __restrict__ Wk,
                                                     const float* __restrict__ Wv,
                                                     __hip_bfloat16* __restrict__ kv) {
    __shared__ float As[32 * 68];  // [k][m], stride 68 (16B-aligned rows)
    __shared__ float Bs[32 * 68];  // [k][n]
    const int rt = blockIdx.x;
    const int bn = blockIdx.y;
    const int tid = threadIdx.x;
    const int lrow = tid >> 2;          // 0..63
    const int koff = (tid & 3) * 8;     // 0,8,16,24
    const int brow = tid >> 3;          // 0..31
    const int bcoff = (tid & 7) * 8;    // 0..56
    const int tm = (tid & 15) * 4;
    const int tn = (tid >> 4) * 4;

    const int row_g = rt * 64 + lrow;
    const float m = meanb[row_g];
    const float r = rstdb[row_g];

    const float* Wsrc;
    int colbase;
    if (bn < 4) { Wsrc = Wk; colbase = bn * 64; }
    else        { Wsrc = Wv; colbase = (bn - 4) * 64; }

    float acc[4][4] = {};

    for (int k0 = 0; k0 < 256; k0 += 32) {
        float4 a0 = *(const float4*)(in + (size_t)row_g * 256 + k0 + koff);
        float4 a1 = *(const float4*)(in + (size_t)row_g * 256 + k0 + koff + 4);
        float vals[8] = {a0.x, a0.y, a0.z, a0.w, a1.x, a1.y, a1.z, a1.w};
#pragma unroll
        for (int i = 0; i < 8; i++) {
            int kk = k0 + koff + i;
            As[(koff + i) * 68 + lrow] = (vals[i] - m) * r * g[kk] + bb[kk];
        }
        float4 b0 = *(const float4*)(Wsrc + (size_t)(k0 + brow) * 256 + colbase + bcoff);
        float4 b1 = *(const float4*)(Wsrc + (size_t)(k0 + brow) * 256 + colbase + bcoff + 4);
        Bs[brow * 68 + bcoff + 0] = b0.x; Bs[brow * 68 + bcoff + 1] = b0.y;
        Bs[brow * 68 + bcoff + 2] = b0.z; Bs[brow * 68 + bcoff + 3] = b0.w;
        Bs[brow * 68 + bcoff + 4] = b1.x; Bs[brow * 68 + bcoff + 5] = b1.y;
        Bs[brow * 68 + bcoff + 6] = b1.z; Bs[brow * 68 + bcoff + 7] = b1.w;
        __syncthreads();
#pragma unroll 8
        for (int k = 0; k < 32; k++) {
            float4 av = *(const float4*)&As[k * 68 + tm];
            float4 bv = *(const float4*)&Bs[k * 68 + tn];
            acc[0][0] += av.x * bv.x; acc[0][1] += av.x * bv.y; acc[0][2] += av.x * bv.z; acc[0][3] += av.x * bv.w;
            acc[1][0] += av.y * bv.x; acc[1][1] += av.y * bv.y; acc[1][2] += av.y * bv.z; acc[1][3] += av.y * bv.w;
            acc[2][0] += av.z * bv.x; acc[2][1] += av.z * bv.y; acc[2][2] += av.z * bv.z; acc[2][3] += av.z * bv.w;
            acc[3][0] += av.w * bv.x; acc[3][1] += av.w * bv.y; acc[3][2] += av.w * bv.z; acc[3][3] += av.w * bv.w;
        }
        __syncthreads();
    }
    const float scale = (bn < 4) ? 0.125f : 1.0f;  // k pre-scaled by hd^-0.5
#pragma unroll
    for (int i = 0; i < 4; i++) {
#pragma unroll
        for (int j = 0; j < 4; j++) {
            int row = rt * 64 + tm + i;
            int col = bn * 64 + tn + j;
            kv[(size_t)row * 512 + col] = __float2bfloat16(acc[i][j] * scale);
        }
    }
}

// -------- 3. slot LN + q projection. grid 512 (b*8+q) x 256 --------
__global__ __launch_bounds__(256) void qproj_kernel(const float* __restrict__ slots,
                                                    const float* __restrict__ g,
                                                    const float* __restrict__ bvec,
                                                    const float* __restrict__ Wq,
                                                    float* __restrict__ qp) {
    int row = blockIdx.x;
    int tid = threadIdx.x;
    __shared__ float s_s[256];
    __shared__ float red[8];
    float x = slots[(size_t)row * 256 + tid];
    float s1 = wred_sum(x);
    float s2 = wred_sum(x * x);
    if ((tid & 63) == 0) { red[tid >> 6] = s1; red[4 + (tid >> 6)] = s2; }
    __syncthreads();
    float m  = (red[0] + red[1] + red[2] + red[3]) * (1.0f / 256.0f);
    float e2 = (red[4] + red[5] + red[6] + red[7]) * (1.0f / 256.0f);
    float rst = rsqrtf(e2 - m * m + LNEPS);
    s_s[tid] = (x - m) * rst * g[tid] + bvec[tid];
    __syncthreads();
    float acc = 0.f;
#pragma unroll 4
    for (int d = 0; d < 256; d++) acc += s_s[d] * Wq[(size_t)d * 256 + tid];
    int b = row >> 3, q = row & 7;
    qp[((size_t)(b * 4 + (tid >> 6)) * 8 + q) * 64 + (tid & 63)] = acc;
}

// -------- 4. logits + joint softmax over (H*NQ)=32 per kv token --------
// grid (128 tiles, 64 b) x 256. Each half-wave (32 lanes) = one token.
__global__ __launch_bounds__(256) void attn_softmax_kernel(const __hip_bfloat16* __restrict__ kv,
                                                           const float* __restrict__ qp,
                                                           float* __restrict__ attnE,
                                                           float* __restrict__ vis,
                                                           int write_vis) {
    int b = blockIdx.y;
    int tile = blockIdx.x;
    int tid = threadIdx.x;
    __shared__ float qs[32 * 65];  // [hq][d], pad 65 to kill bank conflicts
#pragma unroll
    for (int i = 0; i < 8; i++)
        qs[(tid >> 3) * 65 + (tid & 7) * 8 + i] = qp[(size_t)b * 2048 + tid * 8 + i];
    __syncthreads();
    int lane = tid & 63;
    int w = tid >> 6;
    int n = tile * 8 + w * 2 + (lane >> 5);
    int hq = lane & 31;
    int h = hq >> 3, q = hq & 7;
    const __hip_bfloat16* krow = kv + (size_t)(b * 1024 + n) * 512 + h * 64;
    const float* qrow = qs + hq * 65;
    float acc = 0.f;
#pragma unroll 8
    for (int d = 0; d < 64; d++) acc += __bfloat162float(krow[d]) * qrow[d];
    // softmax over the 32 lanes of this half-wave
    float mx = acc;
#pragma unroll
    for (int off = 1; off < 32; off <<= 1) mx = fmaxf(mx, __shfl_xor(mx, off));
    float e = __expf(acc - mx);
    float sm = e;
#pragma unroll
    for (int off = 1; off < 32; off <<= 1) sm += __shfl_xor(sm, off);
    float attn = e / sm;
    attnE[(size_t)(b * 1024 + n) * 32 + hq] = attn + EPS_;
    if (write_vis) {
        float vsum = attn;
        vsum += __shfl_xor(vsum, 8);
        vsum += __shfl_xor(vsum, 16);
        if (h == 0) vis[(size_t)(b * 8 + q) * 1024 + n] = vsum;
    }
}

// -------- 5. colsum over Nkv -> reciprocal. grid 64 x 256 --------
__global__ __launch_bounds__(256) void colsum_kernel(const float* __restrict__ attnE,
                                                     float* __restrict__ recip) {
    int b = blockIdx.x;
    int tid = threadIdx.x;
    int hq = tid & 31;
    int chunk = tid >> 5;  // 0..7
    float s = 0.f;
#pragma unroll 4
    for (int i = 0; i < 128; i++) {
        int n = chunk * 128 + i;
        s += attnE[(size_t)(b * 1024 + n) * 32 + hq];
    }
    __shared__ float red[8][32];
    red[chunk][hq] = s;
    __syncthreads();
    if (tid < 32) {
        float t = 0.f;
#pragma unroll
        for (int c = 0; c < 8; c++) t += red[c][tid];
        recip[b * 32 + tid] = 1.0f / t;
    }
}

// -------- 6. updates = norm(attn) @ v. grid (H=4, B=64) x 256 --------
__global__ __launch_bounds__(256) void updates_kernel(const __hip_bfloat16* __restrict__ kv,
                                                      const float* __restrict__ attnE,
                                                      const float* __restrict__ recip,
                                                      float* __restrict__ updates) {
    int h = blockIdx.x;
    int b = blockIdx.y;
    int tid = threadIdx.x;
    int d = tid & 63;
    int chunk = tid >> 6;  // 0..3
    float acc[8] = {};
    for (int i = 0; i < 256; i++) {
        int n = chunk * 256 + i;
        float vv = __bfloat162float(kv[(size_t)(b * 1024 + n) * 512 + 256 + h * 64 + d]);
        const float* arow = attnE + (size_t)(b * 1024 + n) * 32 + h * 8;
        float4 a01 = *(const float4*)(arow);
        float4 a23 = *(const float4*)(arow + 4);
        acc[0] += a01.x * vv; acc[1] += a01.y * vv; acc[2] += a01.z * vv; acc[3] += a01.w * vv;
        acc[4] += a23.x * vv; acc[5] += a23.y * vv; acc[6] += a23.z * vv; acc[7] += a23.w * vv;
    }
    __shared__ float red[4][8][64];
#pragma unroll
    for (int q = 0; q < 8; q++) red[chunk][q][d] = acc[q];
    __syncthreads();
    if (chunk == 0) {
#pragma unroll
        for (int q = 0; q < 8; q++) {
            float s = red[0][q][d] + red[1][q][d] + red[2][q][d] + red[3][q][d];
            updates[(size_t)(b * 8 + q) * 256 + h * 64 + d] = s * recip[b * 32 + h * 8 + q];
        }
    }
}

// -------- 7. GRU gate GEMMs: xg = updates@w_ih^T + b_ih ; hg = slots@w_hh^T + b_hh --------
// grid (8, 12, 2) x 256, 64x64 tile, BK=64
__global__ __launch_bounds__(256) void gru_gemm_kernel(const float* __restrict__ updates,
                                                       const float* __restrict__ slotsA,
                                                       const float* __restrict__ w_ih,
                                                       const float* __restrict__ w_hh,
                                                       const float* __restrict__ b_ih,
                                                       const float* __restrict__ b_hh,
                                                       float* __restrict__ xg,
                                                       float* __restrict__ hg) {
    const float *A, *W, *bias;
    float* out;
    if (blockIdx.z == 0) { A = updates; W = w_ih; bias = b_ih; out = xg; }
    else                 { A = slotsA;  W = w_hh; bias = b_hh; out = hg; }
    __shared__ float As[64 * 68];  // [k][m]
    __shared__ float Ws[64 * 68];  // [k][j]
    int rt = blockIdx.x, jt = blockIdx.y;
    int tid = threadIdx.x;
    int lrow = tid >> 2;           // 0..63
    int koff = (tid & 3) * 16;     // 0,16,32,48
    int tm = (tid & 15) * 4, tn = (tid >> 4) * 4;
    float acc[4][4] = {};
    for (int k0 = 0; k0 < 256; k0 += 64) {
#pragma unroll
        for (int ii = 0; ii < 16; ii += 4) {
            float4 av = *(const float4*)(A + (size_t)(rt * 64 + lrow) * 256 + k0 + koff + ii);
            As[(koff + ii + 0) * 68 + lrow] = av.x;
            As[(koff + ii + 1) * 68 + lrow] = av.y;
            As[(koff + ii + 2) * 68 + lrow] = av.z;
            As[(koff + ii + 3) * 68 + lrow] = av.w;
            float4 wv = *(const float4*)(W + (size_t)(jt * 64 + lrow) * 256 + k0 + koff + ii);
            Ws[(koff + ii + 0) * 68 + lrow] = wv.x;
            Ws[(koff + ii + 1) * 68 + lrow] = wv.y;
            Ws[(koff + ii + 2) * 68 + lrow] = wv.z;
            Ws[(koff + ii + 3) * 68 + lrow] = wv.w;
        }
        __syncthreads();
#pragma unroll 8
        for (int k = 0; k < 64; k++) {
            float4 av = *(const float4*)&As[k * 68 + tm];
            float4 bv = *(const float4*)&Ws[k * 68 + tn];
            acc[0][0] += av.x * bv.x; acc[0][1] += av.x * bv.y; acc[0][2] += av.x * bv.z; acc[0][3] += av.x * bv.w;
            acc[1][0] += av.y * bv.x; acc[1][1] += av.y * bv.y; acc[1][2] += av.y * bv.z; acc[1][3] += av.y * bv.w;
            acc[2][0] += av.z * bv.x; acc[2][1] += av.z * bv.y; acc[2][2] += av.z * bv.z; acc[2][3] += av.z * bv.w;
            acc[3][0] += av.w * bv.x; acc[3][1] += av.w * bv.y; acc[3][2] += av.w * bv.z; acc[3][3] += av.w * bv.w;
        }
        __syncthreads();
    }
#pragma unroll
    for (int i = 0; i < 4; i++) {
#pragma unroll
        for (int j = 0; j < 4; j++) {
            int rr = rt * 64 + tm + i;
            int jj = jt * 64 + tn + j;
            out[(size_t)rr * 768 + jj] = acc[i][j] + bias[jj];
        }
    }
}

// -------- 8. GRU gates elementwise. grid 512 x 256 --------
__global__ __launch_bounds__(256) void gru_gate_kernel(const float* __restrict__ xg,
                                                       const float* __restrict__ hg,
                                                       const float* __restrict__ slotsA,
                                                       float* __restrict__ slotsB) {
    int idx = blockIdx.x * 256 + threadIdx.x;
    int row = idx >> 8;
    int i = idx & 255;
    float xr = xg[(size_t)row * 768 + i];
    float xz = xg[(size_t)row * 768 + 256 + i];
    float xn = xg[(size_t)row * 768 + 512 + i];
    float hr = hg[(size_t)row * 768 + i];
    float hz = hg[(size_t)row * 768 + 256 + i];
    float hn = hg[(size_t)row * 768 + 512 + i];
    float r = 1.f / (1.f + __expf(-(xr + hr)));
    float z = 1.f / (1.f + __expf(-(xz + hz)));
    float nn = tanhf(xn + r * hn);
    float hp = slotsA[idx];
    slotsB[idx] = (1.f - z) * nn + z * hp;
}

// -------- 9. MLP layer1: hidden = relu(LN(slotsB)@w1 + b1). grid 512 x 256 --------
__global__ __launch_bounds__(256) void mlp1_kernel(const float* __restrict__ slotsB,
                                                   const float* __restrict__ g,
                                                   const float* __restrict__ bvec,
                                                   const float* __restrict__ w1,
                                                   const float* __restrict__ b1,
                                                   float* __restrict__ hidden) {
    int row = blockIdx.x;
    int tid = threadIdx.x;
    __shared__ float m_s[256];
    __shared__ float red[8];
    float x = slotsB[(size_t)row * 256 + tid];
    float s1 = wred_sum(x);
    float s2 = wred_sum(x * x);
    if ((tid & 63) == 0) { red[tid >> 6] = s1; red[4 + (tid >> 6)] = s2; }
    __syncthreads();
    float m  = (red[0] + red[1] + red[2] + red[3]) * (1.0f / 256.0f);
    float e2 = (red[4] + red[5] + red[6] + red[7]) * (1.0f / 256.0f);
    float rst = rsqrtf(e2 - m * m + LNEPS);
    m_s[tid] = (x - m) * rst * g[tid] + bvec[tid];
    __syncthreads();
    float a0 = 0.f, a1 = 0.f;
#pragma unroll 4
    for (int d = 0; d < 256; d++) {
        float mv = m_s[d];
        a0 += mv * w1[(size_t)d * 512 + tid];
        a1 += mv * w1[(size_t)d * 512 + 256 + tid];
    }
    hidden[(size_t)row * 512 + tid]       = fmaxf(a0 + b1[tid], 0.f);
    hidden[(size_t)row * 512 + 256 + tid] = fmaxf(a1 + b1[256 + tid], 0.f);
}

// -------- 10. MLP layer2 + residual. grid 512 x 256 --------
__global__ __launch_bounds__(256) void mlp2_kernel(const float* __restrict__ slotsB,
                                                   const float* __restrict__ hidden,
                                                   const float* __restrict__ w2,
                                                   const float* __restrict__ b2,
                                                   float* __restrict__ out) {
    int row = blockIdx.x;
    int tid = threadIdx.x;
    __shared__ float h_s[512];
    h_s[tid]       = hidden[(size_t)row * 512 + tid];
    h_s[256 + tid] = hidden[(size_t)row * 512 + 256 + tid];
    __syncthreads();
    float acc = 0.f;
#pragma unroll 4
    for (int k = 0; k < 512; k++) acc += h_s[k] * w2[(size_t)k * 256 + tid];
    out[(size_t)row * 256 + tid] = slotsB[(size_t)row * 256 + tid] + acc + b2[tid];
}

// -------- host --------
extern "C" void kernel_launch(void* const* d_in, const int* in_sizes, int n_in,
                              void* d_out, int out_size, void* d_ws, size_t ws_size,
                              hipStream_t stream) {
    const float* inputs   = (const float*)d_in[0];
    const float* slots0   = (const float*)d_in[1];
    const float* ln_in_g  = (const float*)d_in[2];
    const float* ln_in_b  = (const float*)d_in[3];
    const float* ln_sl_g  = (const float*)d_in[4];
    const float* ln_sl_b  = (const float*)d_in[5];
    const float* ln_mlp_g = (const float*)d_in[6];
    const float* ln_mlp_b = (const float*)d_in[7];
    const float* Wq       = (const float*)d_in[8];
    const float* Wk       = (const float*)d_in[9];
    const float* Wv       = (const float*)d_in[10];
    const float* w_ih     = (const float*)d_in[11];
    const float* w_hh     = (const float*)d_in[12];
    const float* b_ih     = (const float*)d_in[13];
    const float* b_hh     = (const float*)d_in[14];
    const float* w1       = (const float*)d_in[15];
    const float* b1       = (const float*)d_in[16];
    const float* w2       = (const float*)d_in[17];
    const float* b2       = (const float*)d_in[18];

    float* out_slots = (float*)d_out;                 // [64,8,256]
    float* out_vis   = (float*)d_out + 64 * 8 * 256;  // [64,8,1024]

    // workspace carve (256B aligned)
    char* p = (char*)d_ws;
    auto carve = [&](size_t bytes) {
        void* r = (void*)p;
        p += (bytes + 255) & ~(size_t)255;
        return r;
    };
    __hip_bfloat16* kv = (__hip_bfloat16*)carve((size_t)65536 * 512 * 2);  // 64 MB
    float* meanb   = (float*)carve(65536 * 4);
    float* rstdb   = (float*)carve(65536 * 4);
    float* qp      = (float*)carve((size_t)64 * 2048 * 4);
    float* attnE   = (float*)carve((size_t)64 * 1024 * 32 * 4);            // 8 MB
    float* recip   = (float*)carve(64 * 32 * 4);
    float* updates = (float*)carve((size_t)512 * 256 * 4);
    float* xg      = (float*)carve((size_t)512 * 768 * 4);
    float* hg      = (float*)carve((size_t)512 * 768 * 4);
    float* hidden  = (float*)carve((size_t)512 * 512 * 4);
    float* slotsA  = (float*)carve((size_t)512 * 256 * 4);
    float* slotsB  = (float*)carve((size_t)512 * 256 * 4);

    hipMemcpyAsync(slotsA, slots0, (size_t)512 * 256 * 4, hipMemcpyDeviceToDevice, stream);

    rowstats_kernel<<<16384, 256, 0, stream>>>(inputs, meanb, rstdb);
    kvproj_kernel<<<dim3(1024, 8), 256, 0, stream>>>(inputs, meanb, rstdb, ln_in_g, ln_in_b,
                                                     Wk, Wv, kv);

    for (int it = 0; it < 3; ++it) {
        qproj_kernel<<<512, 256, 0, stream>>>(slotsA, ln_sl_g, ln_sl_b, Wq, qp);
        attn_softmax_kernel<<<dim3(128, 64), 256, 0, stream>>>(kv, qp, attnE, out_vis,
                                                               (it == 2) ? 1 : 0);
        colsum_kernel<<<64, 256, 0, stream>>>(attnE, recip);
        updates_kernel<<<dim3(4, 64), 256, 0, stream>>>(kv, attnE, recip, updates);
        gru_gemm_kernel<<<dim3(8, 12, 2), 256, 0, stream>>>(updates, slotsA, w_ih, w_hh,
                                                            b_ih, b_hh, xg, hg);
        gru_gate_kernel<<<512, 256, 0, stream>>>(xg, hg, slotsA, slotsB);
        mlp1_kernel<<<512, 256, 0, stream>>>(slotsB, ln_mlp_g, ln_mlp_b, w1, b1, hidden);
        mlp2_kernel<<<512, 256, 0, stream>>>(slotsB, hidden, w2, b2,
                                             (it == 2) ? out_slots : slotsA);
    }
}

// Round 2
// 603.590 us; speedup vs baseline: 1.1057x; 1.1057x over previous
//
#include <hip/hip_runtime.h>
#include <hip/hip_bf16.h>
#include <math.h>

#define EPS_  1e-8f
#define LNEPS 1e-5f

typedef __attribute__((ext_vector_type(8))) short   short8;
typedef __attribute__((ext_vector_type(8))) __bf16  bf16x8;
typedef __attribute__((ext_vector_type(4))) float   f32x4;

typedef unsigned short ushort_t;

__device__ __forceinline__ float bf2f(unsigned int u) { return __uint_as_float(u << 16); }
__device__ __forceinline__ unsigned short f2bf(float f) {
    unsigned int u = __float_as_uint(f);
    u += 0x7fff + ((u >> 16) & 1);
    return (unsigned short)(u >> 16);
}
__device__ __forceinline__ f32x4 mfma_bf16(short8 a, short8 b, f32x4 c) {
    union U { short8 s; bf16x8 b; };
    U ua, ub; ua.s = a; ub.s = b;
    return __builtin_amdgcn_mfma_f32_16x16x32_bf16(ua.b, ub.b, c, 0, 0, 0);
}

__device__ __forceinline__ float wred_sum(float v) {
#pragma unroll
    for (int off = 32; off > 0; off >>= 1) v += __shfl_xor(v, off);
    return v;
}

// -------- 0. prepack weights: Wt[n][k] bf16, n<256 -> Wk[k][n]*0.125, else Wv[k][n-256]
__global__ __launch_bounds__(256) void prepack_w_kernel(const float* __restrict__ Wk,
                                                        const float* __restrict__ Wv,
                                                        ushort_t* __restrict__ Wt) {
    int n = blockIdx.x;   // 0..511
    int k = threadIdx.x;  // 0..255
    float v = (n < 256) ? Wk[(size_t)k * 256 + n] * 0.125f : Wv[(size_t)k * 256 + (n - 256)];
    Wt[(size_t)n * 256 + k] = f2bf(v);
}

// -------- 1. per-row mean/rstd of inputs --------
__global__ __launch_bounds__(256) void rowstats_kernel(const float* __restrict__ in,
                                                       float* __restrict__ meanb,
                                                       float* __restrict__ rstdb) {
    int row  = blockIdx.x * 4 + (threadIdx.x >> 6);
    int lane = threadIdx.x & 63;
    float4 v = *(const float4*)(in + (size_t)row * 256 + lane * 4);
    float s1 = v.x + v.y + v.z + v.w;
    float s2 = v.x * v.x + v.y * v.y + v.z * v.z + v.w * v.w;
    s1 = wred_sum(s1);
    s2 = wred_sum(s2);
    if (lane == 0) {
        float m = s1 * (1.0f / 256.0f);
        float e2 = s2 * (1.0f / 256.0f);
        meanb[row] = m;
        rstdb[row] = rsqrtf(e2 - m * m + LNEPS);
    }
}

// -------- 2. KV projection via MFMA: kv[65536][512] bf16 = LN(in) @ Wt^T --------
// block: 512 threads (8 waves). M-tile 64 rows, N = 512 (all cols). BK=32.
// wave w owns n in [w*64, w*64+64). XOR chunk swizzle: c' = c ^ ((row>>1)&3).
__global__ __launch_bounds__(512) void kvproj_mfma_kernel(const float* __restrict__ in,
                                                          const float* __restrict__ meanb,
                                                          const float* __restrict__ rstdb,
                                                          const float* __restrict__ g,
                                                          const float* __restrict__ bb,
                                                          const ushort_t* __restrict__ Wt,
                                                          ushort_t* __restrict__ kvout) {
    __shared__ __align__(16) ushort_t As[64 * 32];   // 4 KB  [row][32k] swizzled
    __shared__ __align__(16) ushort_t Bs[512 * 32];  // 32 KB [n][32k] swizzled
    const int tid = threadIdx.x;
    const int wv = tid >> 6;   // wave 0..7
    const int l  = tid & 63;
    const int m0 = blockIdx.x * 64;

    const int arow  = tid >> 2;        // 0..127 (only <64 used for A)
    const int akoff = (tid & 3) * 8;   // 0,8,16,24
    float mean = 0.f, rstd = 0.f;
    if (tid < 256) { mean = meanb[m0 + arow]; rstd = rstdb[m0 + arow]; }

    f32x4 zero = {0.f, 0.f, 0.f, 0.f};
    f32x4 acc[4][4];
#pragma unroll
    for (int i = 0; i < 4; i++)
#pragma unroll
        for (int j = 0; j < 4; j++) acc[i][j] = zero;

    for (int k0 = 0; k0 < 256; k0 += 32) {
        if (tid < 256) {
            float4 a0 = *(const float4*)(in + (size_t)(m0 + arow) * 256 + k0 + akoff);
            float4 a1 = *(const float4*)(in + (size_t)(m0 + arow) * 256 + k0 + akoff + 4);
            float4 g0 = *(const float4*)(g + k0 + akoff);
            float4 g1 = *(const float4*)(g + k0 + akoff + 4);
            float4 b0 = *(const float4*)(bb + k0 + akoff);
            float4 b1 = *(const float4*)(bb + k0 + akoff + 4);
            float va[8] = {a0.x, a0.y, a0.z, a0.w, a1.x, a1.y, a1.z, a1.w};
            float vg[8] = {g0.x, g0.y, g0.z, g0.w, g1.x, g1.y, g1.z, g1.w};
            float vb[8] = {b0.x, b0.y, b0.z, b0.w, b1.x, b1.y, b1.z, b1.w};
            short8 pk;
#pragma unroll
            for (int i = 0; i < 8; i++)
                pk[i] = (short)f2bf((va[i] - mean) * rstd * vg[i] + vb[i]);
            int c2 = (akoff >> 3) ^ ((arow >> 1) & 3);
            *(short8*)&As[arow * 32 + c2 * 8] = pk;
        }
        {
            int n = tid;  // 0..511
            const ushort_t* src = Wt + (size_t)n * 256 + k0;
            int sw = (n >> 1) & 3;
#pragma unroll
            for (int c = 0; c < 4; c++)
                *(short8*)&Bs[n * 32 + (c ^ sw) * 8] = *(const short8*)(src + c * 8);
        }
        __syncthreads();
        const int kc = l >> 4;  // 16B chunk 0..3
        short8 af[4], bfr[4];
#pragma unroll
        for (int mi = 0; mi < 4; mi++) {
            int row = (l & 15) + mi * 16;
            af[mi] = *(const short8*)&As[row * 32 + (kc ^ ((row >> 1) & 3)) * 8];
        }
#pragma unroll
        for (int ni = 0; ni < 4; ni++) {
            int n = wv * 64 + ni * 16 + (l & 15);
            bfr[ni] = *(const short8*)&Bs[n * 32 + (kc ^ ((n >> 1) & 3)) * 8];
        }
#pragma unroll
        for (int mi = 0; mi < 4; mi++)
#pragma unroll
            for (int ni = 0; ni < 4; ni++)
                acc[mi][ni] = mfma_bf16(af[mi], bfr[ni], acc[mi][ni]);
        __syncthreads();
    }
#pragma unroll
    for (int mi = 0; mi < 4; mi++)
#pragma unroll
        for (int ni = 0; ni < 4; ni++)
#pragma unroll
            for (int r = 0; r < 4; r++) {
                int row = m0 + mi * 16 + (l >> 4) * 4 + r;
                int col = wv * 64 + ni * 16 + (l & 15);
                kvout[(size_t)row * 512 + col] = f2bf(acc[mi][ni][r]);
            }
}

// -------- 3. slot LN + q projection. grid 512 (b*8+q) x 256 --------
__global__ __launch_bounds__(256) void qproj_kernel(const float* __restrict__ slots,
                                                    const float* __restrict__ g,
                                                    const float* __restrict__ bvec,
                                                    const float* __restrict__ Wq,
                                                    float* __restrict__ qp) {
    int row = blockIdx.x;
    int tid = threadIdx.x;
    __shared__ float s_s[256];
    __shared__ float red[8];
    float x = slots[(size_t)row * 256 + tid];
    float s1 = wred_sum(x);
    float s2 = wred_sum(x * x);
    if ((tid & 63) == 0) { red[tid >> 6] = s1; red[4 + (tid >> 6)] = s2; }
    __syncthreads();
    float m  = (red[0] + red[1] + red[2] + red[3]) * (1.0f / 256.0f);
    float e2 = (red[4] + red[5] + red[6] + red[7]) * (1.0f / 256.0f);
    float rst = rsqrtf(e2 - m * m + LNEPS);
    s_s[tid] = (x - m) * rst * g[tid] + bvec[tid];
    __syncthreads();
    float acc = 0.f;
#pragma unroll 4
    for (int d = 0; d < 256; d++) acc += s_s[d] * Wq[(size_t)d * 256 + tid];
    int b = row >> 3, q = row & 7;
    qp[((size_t)(b * 4 + (tid >> 6)) * 8 + q) * 64 + (tid & 63)] = acc;
}

// -------- 4. logits + joint softmax over 32 (h*q) per kv token --------
__global__ __launch_bounds__(256) void attn_softmax_kernel(const ushort_t* __restrict__ kv,
                                                           const float* __restrict__ qp,
                                                           float* __restrict__ attnE,
                                                           float* __restrict__ vis,
                                                           int write_vis) {
    int b = blockIdx.y;
    int tile = blockIdx.x;
    int tid = threadIdx.x;
    __shared__ float qs[32 * 65];
#pragma unroll
    for (int i = 0; i < 8; i++)
        qs[(tid >> 3) * 65 + (tid & 7) * 8 + i] = qp[(size_t)b * 2048 + tid * 8 + i];
    __syncthreads();
    int lane = tid & 63;
    int w = tid >> 6;
    int n = tile * 8 + w * 2 + (lane >> 5);
    int hq = lane & 31;
    int h = hq >> 3, q = hq & 7;
    const ushort_t* krow = kv + (size_t)(b * 1024 + n) * 512 + h * 64;
    const float* qrow = qs + hq * 65;
    float acc = 0.f;
#pragma unroll
    for (int d8 = 0; d8 < 8; d8++) {
        short8 kk = *(const short8*)(krow + d8 * 8);
#pragma unroll
        for (int j = 0; j < 8; j++)
            acc += bf2f((unsigned short)kk[j]) * qrow[d8 * 8 + j];
    }
    float mx = acc;
#pragma unroll
    for (int off = 1; off < 32; off <<= 1) mx = fmaxf(mx, __shfl_xor(mx, off));
    float e = __expf(acc - mx);
    float sm = e;
#pragma unroll
    for (int off = 1; off < 32; off <<= 1) sm += __shfl_xor(sm, off);
    float attn = e / sm;
    attnE[(size_t)(b * 1024 + n) * 32 + hq] = attn + EPS_;
    if (write_vis) {
        float vsum = attn;
        vsum += __shfl_xor(vsum, 8);
        vsum += __shfl_xor(vsum, 16);
        if (h == 0) vis[(size_t)(b * 8 + q) * 1024 + n] = vsum;
    }
}

// -------- 5. colsum over Nkv -> reciprocal --------
__global__ __launch_bounds__(256) void colsum_kernel(const float* __restrict__ attnE,
                                                     float* __restrict__ recip) {
    int b = blockIdx.x;
    int tid = threadIdx.x;
    int hq = tid & 31;
    int chunk = tid >> 5;
    float s = 0.f;
#pragma unroll 4
    for (int i = 0; i < 128; i++) {
        int n = chunk * 128 + i;
        s += attnE[(size_t)(b * 1024 + n) * 32 + hq];
    }
    __shared__ float red[8][32];
    red[chunk][hq] = s;
    __syncthreads();
    if (tid < 32) {
        float t = 0.f;
#pragma unroll
        for (int c = 0; c < 8; c++) t += red[c][tid];
        recip[b * 32 + tid] = 1.0f / t;
    }
}

// -------- 6. updates = norm(attn) @ v. grid (4 h, 64 b) x 256 --------
__global__ __launch_bounds__(256) void updates_kernel(const ushort_t* __restrict__ kv,
                                                      const float* __restrict__ attnE,
                                                      const float* __restrict__ recip,
                                                      float* __restrict__ updates) {
    int h = blockIdx.x;
    int b = blockIdx.y;
    int tid = threadIdx.x;
    int dp = tid & 31;      // d pair: d = dp*2, dp*2+1
    int chunk = tid >> 5;   // 0..7, 128 n each
    float acc[8][2] = {};
    for (int i = 0; i < 128; i++) {
        int n = chunk * 128 + i;
        unsigned int vpack = *(const unsigned int*)(kv + (size_t)(b * 1024 + n) * 512 + 256 + h * 64 + dp * 2);
        float v0 = bf2f(vpack & 0xffffu);
        float v1 = bf2f(vpack >> 16);
        const float* arow = attnE + (size_t)(b * 1024 + n) * 32 + h * 8;
        float4 a01 = *(const float4*)(arow);
        float4 a23 = *(const float4*)(arow + 4);
        acc[0][0] += a01.x * v0; acc[0][1] += a01.x * v1;
        acc[1][0] += a01.y * v0; acc[1][1] += a01.y * v1;
        acc[2][0] += a01.z * v0; acc[2][1] += a01.z * v1;
        acc[3][0] += a01.w * v0; acc[3][1] += a01.w * v1;
        acc[4][0] += a23.x * v0; acc[4][1] += a23.x * v1;
        acc[5][0] += a23.y * v0; acc[5][1] += a23.y * v1;
        acc[6][0] += a23.z * v0; acc[6][1] += a23.z * v1;
        acc[7][0] += a23.w * v0; acc[7][1] += a23.w * v1;
    }
    __shared__ float red[8][8][64];  // 16 KB
#pragma unroll
    for (int q = 0; q < 8; q++) {
        red[chunk][q][dp * 2]     = acc[q][0];
        red[chunk][q][dp * 2 + 1] = acc[q][1];
    }
    __syncthreads();
    int d = tid & 63;
    int qsel = tid >> 6;  // 0..3
#pragma unroll
    for (int qq = qsel; qq < 8; qq += 4) {
        float s = 0.f;
#pragma unroll
        for (int c = 0; c < 8; c++) s += red[c][qq][d];
        updates[(size_t)(b * 8 + qq) * 256 + h * 64 + d] = s * recip[b * 32 + h * 8 + qq];
    }
}

// -------- 7. GRU gate GEMMs --------
__global__ __launch_bounds__(256) void gru_gemm_kernel(const float* __restrict__ updates,
                                                       const float* __restrict__ slotsA,
                                                       const float* __restrict__ w_ih,
                                                       const float* __restrict__ w_hh,
                                                       const float* __restrict__ b_ih,
                                                       const float* __restrict__ b_hh,
                                                       float* __restrict__ xg,
                                                       float* __restrict__ hg) {
    const float *A, *W, *bias;
    float* out;
    if (blockIdx.z == 0) { A = updates; W = w_ih; bias = b_ih; out = xg; }
    else                 { A = slotsA;  W = w_hh; bias = b_hh; out = hg; }
    __shared__ float As[64 * 68];
    __shared__ float Ws[64 * 68];
    int rt = blockIdx.x, jt = blockIdx.y;
    int tid = threadIdx.x;
    int lrow = tid >> 2;
    int koff = (tid & 3) * 16;
    int tm = (tid & 15) * 4, tn = (tid >> 4) * 4;
    float acc[4][4] = {};
    for (int k0 = 0; k0 < 256; k0 += 64) {
#pragma unroll
        for (int ii = 0; ii < 16; ii += 4) {
            float4 av = *(const float4*)(A + (size_t)(rt * 64 + lrow) * 256 + k0 + koff + ii);
            As[(koff + ii + 0) * 68 + lrow] = av.x;
            As[(koff + ii + 1) * 68 + lrow] = av.y;
            As[(koff + ii + 2) * 68 + lrow] = av.z;
            As[(koff + ii + 3) * 68 + lrow] = av.w;
            float4 wv = *(const float4*)(W + (size_t)(jt * 64 + lrow) * 256 + k0 + koff + ii);
            Ws[(koff + ii + 0) * 68 + lrow] = wv.x;
            Ws[(koff + ii + 1) * 68 + lrow] = wv.y;
            Ws[(koff + ii + 2) * 68 + lrow] = wv.z;
            Ws[(koff + ii + 3) * 68 + lrow] = wv.w;
        }
        __syncthreads();
#pragma unroll 8
        for (int k = 0; k < 64; k++) {
            float4 av = *(const float4*)&As[k * 68 + tm];
            float4 bv = *(const float4*)&Ws[k * 68 + tn];
            acc[0][0] += av.x * bv.x; acc[0][1] += av.x * bv.y; acc[0][2] += av.x * bv.z; acc[0][3] += av.x * bv.w;
            acc[1][0] += av.y * bv.x; acc[1][1] += av.y * bv.y; acc[1][2] += av.y * bv.z; acc[1][3] += av.y * bv.w;
            acc[2][0] += av.z * bv.x; acc[2][1] += av.z * bv.y; acc[2][2] += av.z * bv.z; acc[2][3] += av.z * bv.w;
            acc[3][0] += av.w * bv.x; acc[3][1] += av.w * bv.y; acc[3][2] += av.w * bv.z; acc[3][3] += av.w * bv.w;
        }
        __syncthreads();
    }
#pragma unroll
    for (int i = 0; i < 4; i++)
#pragma unroll
        for (int j = 0; j < 4; j++) {
            int rr = rt * 64 + tm + i;
            int jj = jt * 64 + tn + j;
            out[(size_t)rr * 768 + jj] = acc[i][j] + bias[jj];
        }
}

// -------- 8. GRU gates elementwise --------
__global__ __launch_bounds__(256) void gru_gate_kernel(const float* __restrict__ xg,
                                                       const float* __restrict__ hg,
                                                       const float* __restrict__ slotsA,
                                                       float* __restrict__ slotsB) {
    int idx = blockIdx.x * 256 + threadIdx.x;
    int row = idx >> 8;
    int i = idx & 255;
    float xr = xg[(size_t)row * 768 + i];
    float xz = xg[(size_t)row * 768 + 256 + i];
    float xn = xg[(size_t)row * 768 + 512 + i];
    float hr = hg[(size_t)row * 768 + i];
    float hz = hg[(size_t)row * 768 + 256 + i];
    float hn = hg[(size_t)row * 768 + 512 + i];
    float r = 1.f / (1.f + __expf(-(xr + hr)));
    float z = 1.f / (1.f + __expf(-(xz + hz)));
    float nn = tanhf(xn + r * hn);
    float hp = slotsA[idx];
    slotsB[idx] = (1.f - z) * nn + z * hp;
}

// -------- 9. MLP layer1 --------
__global__ __launch_bounds__(256) void mlp1_kernel(const float* __restrict__ slotsB,
                                                   const float* __restrict__ g,
                                                   const float* __restrict__ bvec,
                                                   const float* __restrict__ w1,
                                                   const float* __restrict__ b1,
                                                   float* __restrict__ hidden) {
    int row = blockIdx.x;
    int tid = threadIdx.x;
    __shared__ float m_s[256];
    __shared__ float red[8];
    float x = slotsB[(size_t)row * 256 + tid];
    float s1 = wred_sum(x);
    float s2 = wred_sum(x * x);
    if ((tid & 63) == 0) { red[tid >> 6] = s1; red[4 + (tid >> 6)] = s2; }
    __syncthreads();
    float m  = (red[0] + red[1] + red[2] + red[3]) * (1.0f / 256.0f);
    float e2 = (red[4] + red[5] + red[6] + red[7]) * (1.0f / 256.0f);
    float rst = rsqrtf(e2 - m * m + LNEPS);
    m_s[tid] = (x - m) * rst * g[tid] + bvec[tid];
    __syncthreads();
    float a0 = 0.f, a1 = 0.f;
#pragma unroll 4
    for (int d = 0; d < 256; d++) {
        float mv = m_s[d];
        a0 += mv * w1[(size_t)d * 512 + tid];
        a1 += mv * w1[(size_t)d * 512 + 256 + tid];
    }
    hidden[(size_t)row * 512 + tid]       = fmaxf(a0 + b1[tid], 0.f);
    hidden[(size_t)row * 512 + 256 + tid] = fmaxf(a1 + b1[256 + tid], 0.f);
}

// -------- 10. MLP layer2 + residual --------
__global__ __launch_bounds__(256) void mlp2_kernel(const float* __restrict__ slotsB,
                                                   const float* __restrict__ hidden,
                                                   const float* __restrict__ w2,
                                                   const float* __restrict__ b2,
                                                   float* __restrict__ out) {
    int row = blockIdx.x;
    int tid = threadIdx.x;
    __shared__ float h_s[512];
    h_s[tid]       = hidden[(size_t)row * 512 + tid];
    h_s[256 + tid] = hidden[(size_t)row * 512 + 256 + tid];
    __syncthreads();
    float acc = 0.f;
#pragma unroll 4
    for (int k = 0; k < 512; k++) acc += h_s[k] * w2[(size_t)k * 256 + tid];
    out[(size_t)row * 256 + tid] = slotsB[(size_t)row * 256 + tid] + acc + b2[tid];
}

// -------- host --------
extern "C" void kernel_launch(void* const* d_in, const int* in_sizes, int n_in,
                              void* d_out, int out_size, void* d_ws, size_t ws_size,
                              hipStream_t stream) {
    const float* inputs   = (const float*)d_in[0];
    const float* slots0   = (const float*)d_in[1];
    const float* ln_in_g  = (const float*)d_in[2];
    const float* ln_in_b  = (const float*)d_in[3];
    const float* ln_sl_g  = (const float*)d_in[4];
    const float* ln_sl_b  = (const float*)d_in[5];
    const float* ln_mlp_g = (const float*)d_in[6];
    const float* ln_mlp_b = (const float*)d_in[7];
    const float* Wq       = (const float*)d_in[8];
    const float* Wk       = (const float*)d_in[9];
    const float* Wv       = (const float*)d_in[10];
    const float* w_ih     = (const float*)d_in[11];
    const float* w_hh     = (const float*)d_in[12];
    const float* b_ih     = (const float*)d_in[13];
    const float* b_hh     = (const float*)d_in[14];
    const float* w1       = (const float*)d_in[15];
    const float* b1       = (const float*)d_in[16];
    const float* w2       = (const float*)d_in[17];
    const float* b2       = (const float*)d_in[18];

    float* out_slots = (float*)d_out;
    float* out_vis   = (float*)d_out + 64 * 8 * 256;

    char* p = (char*)d_ws;
    auto carve = [&](size_t bytes) {
        void* r = (void*)p;
        p += (bytes + 255) & ~(size_t)255;
        return r;
    };
    ushort_t* kv   = (ushort_t*)carve((size_t)65536 * 512 * 2);  // 64 MB
    ushort_t* Wt   = (ushort_t*)carve((size_t)512 * 256 * 2);    // 256 KB
    float* meanb   = (float*)carve(65536 * 4);
    float* rstdb   = (float*)carve(65536 * 4);
    float* qp      = (float*)carve((size_t)64 * 2048 * 4);
    float* attnE   = (float*)carve((size_t)64 * 1024 * 32 * 4);  // 8 MB
    float* recip   = (float*)carve(64 * 32 * 4);
    float* updates = (float*)carve((size_t)512 * 256 * 4);
    float* xg      = (float*)carve((size_t)512 * 768 * 4);
    float* hg      = (float*)carve((size_t)512 * 768 * 4);
    float* hidden  = (float*)carve((size_t)512 * 512 * 4);
    float* slotsA  = (float*)carve((size_t)512 * 256 * 4);
    float* slotsB  = (float*)carve((size_t)512 * 256 * 4);

    hipMemcpyAsync(slotsA, slots0, (size_t)512 * 256 * 4, hipMemcpyDeviceToDevice, stream);

    prepack_w_kernel<<<512, 256, 0, stream>>>(Wk, Wv, Wt);
    rowstats_kernel<<<16384, 256, 0, stream>>>(inputs, meanb, rstdb);
    kvproj_mfma_kernel<<<1024, 512, 0, stream>>>(inputs, meanb, rstdb, ln_in_g, ln_in_b, Wt, kv);

    for (int it = 0; it < 3; ++it) {
        qproj_kernel<<<512, 256, 0, stream>>>(slotsA, ln_sl_g, ln_sl_b, Wq, qp);
        attn_softmax_kernel<<<dim3(128, 64), 256, 0, stream>>>(kv, qp, attnE, out_vis,
                                                               (it == 2) ? 1 : 0);
        colsum_kernel<<<64, 256, 0, stream>>>(attnE, recip);
        updates_kernel<<<dim3(4, 64), 256, 0, stream>>>(kv, attnE, recip, updates);
        gru_gemm_kernel<<<dim3(8, 12, 2), 256, 0, stream>>>(updates, slotsA, w_ih, w_hh,
                                                            b_ih, b_hh, xg, hg);
        gru_gate_kernel<<<512, 256, 0, stream>>>(xg, hg, slotsA, slotsB);
        mlp1_kernel<<<512, 256, 0, stream>>>(slotsB, ln_mlp_g, ln_mlp_b, w1, b1, hidden);
        mlp2_kernel<<<512, 256, 0, stream>>>(slotsB, hidden, w2, b2,
                                             (it == 2) ? out_slots : slotsA);
    }
}

// Round 3
// 593.547 us; speedup vs baseline: 1.1244x; 1.0169x over previous
//
#include <hip/hip_runtime.h>
#include <hip/hip_bf16.h>
#include <math.h>

#define EPS_  1e-8f
#define LNEPS 1e-5f

typedef __attribute__((ext_vector_type(8))) short   short8;
typedef __attribute__((ext_vector_type(8))) __bf16  bf16x8;
typedef __attribute__((ext_vector_type(4))) float   f32x4;

typedef unsigned short ushort_t;

__device__ __forceinline__ float bf2f(unsigned int u) { return __uint_as_float(u << 16); }
__device__ __forceinline__ unsigned short f2bf(float f) {
    unsigned int u = __float_as_uint(f);
    u += 0x7fff + ((u >> 16) & 1);
    return (unsigned short)(u >> 16);
}
__device__ __forceinline__ f32x4 mfma_bf16(short8 a, short8 b, f32x4 c) {
    union U { short8 s; bf16x8 b; };
    U ua, ub; ua.s = a; ub.s = b;
    return __builtin_amdgcn_mfma_f32_16x16x32_bf16(ua.b, ub.b, c, 0, 0, 0);
}
__device__ __forceinline__ float wred_sum(float v) {
#pragma unroll
    for (int off = 32; off > 0; off >>= 1) v += __shfl_xor(v, off);
    return v;
}

// -------- prepack Wk/Wv -> Wt[n][k] bf16 (k pre-scaled 0.125) --------
__global__ __launch_bounds__(256) void prepack_w_kernel(const float* __restrict__ Wk,
                                                        const float* __restrict__ Wv,
                                                        ushort_t* __restrict__ Wt) {
    int n = blockIdx.x;
    int k = threadIdx.x;
    float v = (n < 256) ? Wk[(size_t)k * 256 + n] * 0.125f : Wv[(size_t)k * 256 + (n - 256)];
    Wt[(size_t)n * 256 + k] = f2bf(v);
}

// -------- prepack GRU weights transposed: wT[k][j] f32 --------
__global__ __launch_bounds__(256) void prepack_gru_kernel(const float* __restrict__ w_ih,
                                                          const float* __restrict__ w_hh,
                                                          float* __restrict__ w_ihT,
                                                          float* __restrict__ w_hhT) {
    __shared__ float tile[64][65];
    const float* src = blockIdx.z ? w_hh : w_ih;  // [768][256]
    float* dst       = blockIdx.z ? w_hhT : w_ihT;  // [256][768]
    int j0 = blockIdx.x * 64;
    int k0 = blockIdx.y * 64;
    int a = threadIdx.x & 63, b4 = threadIdx.x >> 6;
#pragma unroll
    for (int p = 0; p < 16; ++p) {
        int jj = b4 * 16 + p;
        tile[jj][a] = src[(size_t)(j0 + jj) * 256 + k0 + a];
    }
    __syncthreads();
#pragma unroll
    for (int p = 0; p < 16; ++p) {
        int kk = b4 * 16 + p;
        dst[(size_t)(k0 + kk) * 768 + j0 + a] = tile[a][kk];
    }
}

// -------- per-row mean/rstd of inputs --------
__global__ __launch_bounds__(256) void rowstats_kernel(const float* __restrict__ in,
                                                       float* __restrict__ meanb,
                                                       float* __restrict__ rstdb) {
    int row  = blockIdx.x * 4 + (threadIdx.x >> 6);
    int lane = threadIdx.x & 63;
    float4 v = *(const float4*)(in + (size_t)row * 256 + lane * 4);
    float s1 = v.x + v.y + v.z + v.w;
    float s2 = v.x * v.x + v.y * v.y + v.z * v.z + v.w * v.w;
    s1 = wred_sum(s1);
    s2 = wred_sum(s2);
    if (lane == 0) {
        float m = s1 * (1.0f / 256.0f);
        float e2 = s2 * (1.0f / 256.0f);
        meanb[row] = m;
        rstdb[row] = rsqrtf(e2 - m * m + LNEPS);
    }
}

// -------- KV projection via MFMA, register-double-buffered staging --------
__global__ __launch_bounds__(512) void kvproj_mfma_kernel(const float* __restrict__ in,
                                                          const float* __restrict__ meanb,
                                                          const float* __restrict__ rstdb,
                                                          const float* __restrict__ g,
                                                          const float* __restrict__ bb,
                                                          const ushort_t* __restrict__ Wt,
                                                          ushort_t* __restrict__ kvout) {
    __shared__ __align__(16) ushort_t As[64 * 32];
    __shared__ __align__(16) ushort_t Bs[512 * 32];
    const int tid = threadIdx.x;
    const int wv = tid >> 6;
    const int l  = tid & 63;
    const int m0 = blockIdx.x * 64;

    const int arow  = tid >> 2;
    const int akoff = (tid & 3) * 8;
    float mean = 0.f, rstd = 0.f;
    if (tid < 256) { mean = meanb[m0 + arow]; rstd = rstdb[m0 + arow]; }

    f32x4 zero = {0.f, 0.f, 0.f, 0.f};
    f32x4 acc[4][4];
#pragma unroll
    for (int i = 0; i < 4; i++)
#pragma unroll
        for (int j = 0; j < 4; j++) acc[i][j] = zero;

    // prefetch regs
    float4 pa0, pa1, pg0, pg1, pb0, pb1;
    short8 pw[4];
    const int bsw = (tid >> 1) & 3;  // B swizzle sel for n=tid

    // initial load k0=0
    if (tid < 256) {
        pa0 = *(const float4*)(in + (size_t)(m0 + arow) * 256 + akoff);
        pa1 = *(const float4*)(in + (size_t)(m0 + arow) * 256 + akoff + 4);
        pg0 = *(const float4*)(g + akoff);  pg1 = *(const float4*)(g + akoff + 4);
        pb0 = *(const float4*)(bb + akoff); pb1 = *(const float4*)(bb + akoff + 4);
    }
    {
        const ushort_t* src = Wt + (size_t)tid * 256;
#pragma unroll
        for (int c = 0; c < 4; c++) pw[c] = *(const short8*)(src + c * 8);
    }

    for (int k0 = 0; k0 < 256; k0 += 32) {
        __syncthreads();  // previous MFMA phase done with LDS
        if (tid < 256) {
            float va[8] = {pa0.x, pa0.y, pa0.z, pa0.w, pa1.x, pa1.y, pa1.z, pa1.w};
            float vg[8] = {pg0.x, pg0.y, pg0.z, pg0.w, pg1.x, pg1.y, pg1.z, pg1.w};
            float vb[8] = {pb0.x, pb0.y, pb0.z, pb0.w, pb1.x, pb1.y, pb1.z, pb1.w};
            short8 pk;
#pragma unroll
            for (int i = 0; i < 8; i++)
                pk[i] = (short)f2bf((va[i] - mean) * rstd * vg[i] + vb[i]);
            int c2 = (akoff >> 3) ^ ((arow >> 1) & 3);
            *(short8*)&As[arow * 32 + c2 * 8] = pk;
        }
#pragma unroll
        for (int c = 0; c < 4; c++)
            *(short8*)&Bs[tid * 32 + (c ^ bsw) * 8] = pw[c];
        // prefetch next k-step (overlaps barrier + MFMA below)
        if (k0 + 32 < 256) {
            int kn = k0 + 32;
            if (tid < 256) {
                pa0 = *(const float4*)(in + (size_t)(m0 + arow) * 256 + kn + akoff);
                pa1 = *(const float4*)(in + (size_t)(m0 + arow) * 256 + kn + akoff + 4);
                pg0 = *(const float4*)(g + kn + akoff);  pg1 = *(const float4*)(g + kn + akoff + 4);
                pb0 = *(const float4*)(bb + kn + akoff); pb1 = *(const float4*)(bb + kn + akoff + 4);
            }
            const ushort_t* src = Wt + (size_t)tid * 256 + kn;
#pragma unroll
            for (int c = 0; c < 4; c++) pw[c] = *(const short8*)(src + c * 8);
        }
        __syncthreads();
        const int kc = l >> 4;
        short8 af[4], bfr[4];
#pragma unroll
        for (int mi = 0; mi < 4; mi++) {
            int row = (l & 15) + mi * 16;
            af[mi] = *(const short8*)&As[row * 32 + (kc ^ ((row >> 1) & 3)) * 8];
        }
#pragma unroll
        for (int ni = 0; ni < 4; ni++) {
            int n = wv * 64 + ni * 16 + (l & 15);
            bfr[ni] = *(const short8*)&Bs[n * 32 + (kc ^ ((n >> 1) & 3)) * 8];
        }
#pragma unroll
        for (int mi = 0; mi < 4; mi++)
#pragma unroll
            for (int ni = 0; ni < 4; ni++)
                acc[mi][ni] = mfma_bf16(af[mi], bfr[ni], acc[mi][ni]);
    }
#pragma unroll
    for (int mi = 0; mi < 4; mi++)
#pragma unroll
        for (int ni = 0; ni < 4; ni++)
#pragma unroll
            for (int r = 0; r < 4; r++) {
                int row = m0 + mi * 16 + (l >> 4) * 4 + r;
                int col = wv * 64 + ni * 16 + (l & 15);
                kvout[(size_t)row * 512 + col] = f2bf(acc[mi][ni][r]);
            }
}

// -------- initial slot LN + q projection (used once). grid 512 x 256 --------
__global__ __launch_bounds__(256) void qproj_kernel(const float* __restrict__ slots,
                                                    const float* __restrict__ g,
                                                    const float* __restrict__ bvec,
                                                    const float* __restrict__ Wq,
                                                    float* __restrict__ qp) {
    int row = blockIdx.x;
    int tid = threadIdx.x;
    __shared__ float s_s[256];
    __shared__ float red[8];
    float x = slots[(size_t)row * 256 + tid];
    float s1 = wred_sum(x);
    float s2 = wred_sum(x * x);
    if ((tid & 63) == 0) { red[tid >> 6] = s1; red[4 + (tid >> 6)] = s2; }
    __syncthreads();
    float m  = (red[0] + red[1] + red[2] + red[3]) * (1.0f / 256.0f);
    float e2 = (red[4] + red[5] + red[6] + red[7]) * (1.0f / 256.0f);
    float rst = rsqrtf(e2 - m * m + LNEPS);
    s_s[tid] = (x - m) * rst * g[tid] + bvec[tid];
    __syncthreads();
    float acc = 0.f;
#pragma unroll 4
    for (int d = 0; d < 256; d++) acc += s_s[d] * Wq[(size_t)d * 256 + tid];
    int b = row >> 3, q = row & 7;
    qp[((size_t)(b * 4 + (tid >> 6)) * 8 + q) * 64 + (tid & 63)] = acc;
}

// -------- fused attention: logits + joint softmax + colsum + unnormalized updates --------
// grid (8 chunks of 128 tokens, 64 b) x 256 threads.
__global__ __launch_bounds__(256) void attn_fused_kernel(const ushort_t* __restrict__ kv,
                                                         const float* __restrict__ qp,
                                                         float* __restrict__ Upart,
                                                         float* __restrict__ Cpart,
                                                         float* __restrict__ vis,
                                                         int write_vis) {
    int b = blockIdx.y;
    int chunk = blockIdx.x;
    int tid = threadIdx.x;
    __shared__ float qs[32 * 65];
    __shared__ float att[8][32];
    __shared__ float cred[4][32];
#pragma unroll
    for (int i = 0; i < 8; i++)
        qs[(tid >> 3) * 65 + (tid & 7) * 8 + i] = qp[(size_t)b * 2048 + tid * 8 + i];
    __syncthreads();

    const int lane = tid & 63;
    const int w = tid >> 6;
    const int hq = lane & 31;
    const int h_l = hq >> 3, q_l = hq & 7;
    const int tloc = w * 2 + (lane >> 5);  // local token slot 0..7 per group
    const int h_u = tid >> 6, d_u = tid & 63;

    float creg = 0.f;
    float U[8] = {0.f, 0.f, 0.f, 0.f, 0.f, 0.f, 0.f, 0.f};
    const float* qrow = qs + hq * 65;

    for (int grp = 0; grp < 16; ++grp) {
        // ---- phase 1: logits + softmax for 8 tokens (half-wave per token) ----
        int n = chunk * 128 + grp * 8 + tloc;
        const ushort_t* krow = kv + (size_t)(b * 1024 + n) * 512 + h_l * 64;
        float acc = 0.f;
#pragma unroll
        for (int d8 = 0; d8 < 8; d8++) {
            short8 kk = *(const short8*)(krow + d8 * 8);
#pragma unroll
            for (int j = 0; j < 8; j++)
                acc += bf2f((unsigned short)kk[j]) * qrow[d8 * 8 + j];
        }
        float mx = acc;
#pragma unroll
        for (int off = 1; off < 32; off <<= 1) mx = fmaxf(mx, __shfl_xor(mx, off));
        float e = __expf(acc - mx);
        float sm = e;
#pragma unroll
        for (int off = 1; off < 32; off <<= 1) sm += __shfl_xor(sm, off);
        float attn = e / sm;
        float attE = attn + EPS_;
        att[tloc][hq] = attE;
        creg += attE;
        if (write_vis) {
            float vsum = attn;
            vsum += __shfl_xor(vsum, 8);
            vsum += __shfl_xor(vsum, 16);
            if (h_l == 0) vis[(size_t)(b * 8 + q_l) * 1024 + n] = vsum;
        }
        __syncthreads();
        // ---- phase 2: U[q] += attE * v over the 8 tokens ----
        const ushort_t* vrow = kv + (size_t)(b * 1024 + chunk * 128 + grp * 8) * 512 + 256 + h_u * 64 + d_u;
#pragma unroll
        for (int t2 = 0; t2 < 8; t2++) {
            float vv = bf2f(vrow[(size_t)t2 * 512]);
            float4 a01 = *(const float4*)&att[t2][h_u * 8];
            float4 a23 = *(const float4*)&att[t2][h_u * 8 + 4];
            U[0] += a01.x * vv; U[1] += a01.y * vv; U[2] += a01.z * vv; U[3] += a01.w * vv;
            U[4] += a23.x * vv; U[5] += a23.y * vv; U[6] += a23.z * vv; U[7] += a23.w * vv;
        }
        __syncthreads();
    }
    // colsum partial: combine lane & lane+32 (same hq), then 4 waves
    creg += __shfl_xor(creg, 32);
    if (lane < 32) cred[w][hq] = creg;
    __syncthreads();
    if (tid < 32)
        Cpart[(size_t)(b * 8 + chunk) * 32 + tid] =
            cred[0][tid] + cred[1][tid] + cred[2][tid] + cred[3][tid];
    // U partials
#pragma unroll
    for (int q = 0; q < 8; q++)
        Upart[(size_t)(b * 8 + chunk) * 2048 + q * 256 + h_u * 64 + d_u] = U[q];
}

// -------- reduce partials + normalize: updates[b*8+q][256] --------
__global__ __launch_bounds__(256) void updates_reduce_kernel(const float* __restrict__ Upart,
                                                             const float* __restrict__ Cpart,
                                                             float* __restrict__ updates) {
    int b = blockIdx.x;
    int tid = threadIdx.x;
    __shared__ float recip_s[32];
    if (tid < 32) {
        float c = 0.f;
#pragma unroll
        for (int p = 0; p < 8; p++) c += Cpart[(size_t)(b * 8 + p) * 32 + tid];
        recip_s[tid] = 1.0f / c;
    }
    __syncthreads();
    int h = tid >> 6;
#pragma unroll
    for (int q = 0; q < 8; q++) {
        float s = 0.f;
#pragma unroll
        for (int p = 0; p < 8; p++)
            s += Upart[(size_t)(b * 8 + p) * 2048 + q * 256 + tid];
        updates[(size_t)(b * 8 + q) * 256 + tid] = s * recip_s[h * 8 + q];
    }
}

// -------- fused slot update: GRU + gates + LN + MLP + residual + next qproj --------
// grid 128 x 256 threads; 4 slot-rows per block.
__global__ __launch_bounds__(256) void slot_fused_kernel(const float* __restrict__ updates,
                                                         const float* __restrict__ slotsIn,
                                                         const float* __restrict__ w_ihT,
                                                         const float* __restrict__ w_hhT,
                                                         const float* __restrict__ b_ih,
                                                         const float* __restrict__ b_hh,
                                                         const float* __restrict__ ln_mlp_g,
                                                         const float* __restrict__ ln_mlp_b,
                                                         const float* __restrict__ w1,
                                                         const float* __restrict__ b1,
                                                         const float* __restrict__ w2,
                                                         const float* __restrict__ b2,
                                                         const float* __restrict__ ln_sl_g,
                                                         const float* __restrict__ ln_sl_b,
                                                         const float* __restrict__ Wq,
                                                         float* __restrict__ slotsOut,
                                                         float* __restrict__ qp,
                                                         int emit_qp) {
    __shared__ float U_s[4][256], H_s[4][256], SB_s[4][256], M_s[4][256];
    __shared__ float hid_s[4][512];
    __shared__ float redA[4][4], redB[4][4];
    const int tid = threadIdx.x;
    const int lane = tid & 63, wv = tid >> 6;
    const int r0 = blockIdx.x * 4;

    ((float4*)&U_s[0][0])[tid] = ((const float4*)(updates + (size_t)r0 * 256))[tid];
    ((float4*)&H_s[0][0])[tid] = ((const float4*)(slotsIn + (size_t)r0 * 256))[tid];
    __syncthreads();

    // ---- GRU GEMVs: thread owns cols {tid, tid+256, tid+512} for 4 rows ----
    float xg0[4], xg1[4], xg2[4], hg0[4], hg1[4], hg2[4];
    {
        float bi0 = b_ih[tid], bi1 = b_ih[256 + tid], bi2 = b_ih[512 + tid];
        float bh0 = b_hh[tid], bh1 = b_hh[256 + tid], bh2 = b_hh[512 + tid];
#pragma unroll
        for (int r = 0; r < 4; r++) {
            xg0[r] = bi0; xg1[r] = bi1; xg2[r] = bi2;
            hg0[r] = bh0; hg1[r] = bh1; hg2[r] = bh2;
        }
    }
#pragma unroll 4
    for (int k = 0; k < 256; k++) {
        float wi0 = w_ihT[(size_t)k * 768 + tid];
        float wi1 = w_ihT[(size_t)k * 768 + 256 + tid];
        float wi2 = w_ihT[(size_t)k * 768 + 512 + tid];
        float wh0 = w_hhT[(size_t)k * 768 + tid];
        float wh1 = w_hhT[(size_t)k * 768 + 256 + tid];
        float wh2 = w_hhT[(size_t)k * 768 + 512 + tid];
#pragma unroll
        for (int r = 0; r < 4; r++) {
            float u = U_s[r][k], hh = H_s[r][k];
            xg0[r] += u * wi0; xg1[r] += u * wi1; xg2[r] += u * wi2;
            hg0[r] += hh * wh0; hg1[r] += hh * wh1; hg2[r] += hh * wh2;
        }
    }
    // ---- gates ----
    float sb[4];
#pragma unroll
    for (int r = 0; r < 4; r++) {
        float rg = 1.f / (1.f + __expf(-(xg0[r] + hg0[r])));
        float z  = 1.f / (1.f + __expf(-(xg1[r] + hg1[r])));
        float nn = tanhf(xg2[r] + rg * hg2[r]);
        sb[r] = (1.f - z) * nn + z * H_s[r][tid];
        SB_s[r][tid] = sb[r];
    }
    // ---- LN(SB) with ln_mlp -> M_s ----
    {
        float s1[4], s2[4];
#pragma unroll
        for (int r = 0; r < 4; r++) { s1[r] = wred_sum(sb[r]); s2[r] = wred_sum(sb[r] * sb[r]); }
        if (lane == 0)
#pragma unroll
            for (int r = 0; r < 4; r++) { redA[wv][r] = s1[r]; redB[wv][r] = s2[r]; }
        __syncthreads();
        float gg = ln_mlp_g[tid], bbv = ln_mlp_b[tid];
#pragma unroll
        for (int r = 0; r < 4; r++) {
            float m  = (redA[0][r] + redA[1][r] + redA[2][r] + redA[3][r]) * (1.f / 256.f);
            float e2 = (redB[0][r] + redB[1][r] + redB[2][r] + redB[3][r]) * (1.f / 256.f);
            float rst = rsqrtf(e2 - m * m + LNEPS);
            M_s[r][tid] = (sb[r] - m) * rst * gg + bbv;
        }
        __syncthreads();
    }
    // ---- MLP layer 1 ----
    float h1a[4], h1b[4];
    {
        float bb1a = b1[tid], bb1b = b1[256 + tid];
#pragma unroll
        for (int r = 0; r < 4; r++) { h1a[r] = bb1a; h1b[r] = bb1b; }
    }
#pragma unroll 4
    for (int k = 0; k < 256; k++) {
        float wa = w1[(size_t)k * 512 + tid];
        float wb = w1[(size_t)k * 512 + 256 + tid];
#pragma unroll
        for (int r = 0; r < 4; r++) {
            float mv = M_s[r][k];
            h1a[r] += mv * wa; h1b[r] += mv * wb;
        }
    }
#pragma unroll
    for (int r = 0; r < 4; r++) {
        hid_s[r][tid]       = fmaxf(h1a[r], 0.f);
        hid_s[r][256 + tid] = fmaxf(h1b[r], 0.f);
    }
    __syncthreads();
    // ---- MLP layer 2 + residual ----
    float outv[4];
    {
        float bb2 = b2[tid];
#pragma unroll
        for (int r = 0; r < 4; r++) outv[r] = bb2;
    }
#pragma unroll 4
    for (int k = 0; k < 512; k++) {
        float wv2 = w2[(size_t)k * 256 + tid];
#pragma unroll
        for (int r = 0; r < 4; r++) outv[r] += hid_s[r][k] * wv2;
    }
#pragma unroll
    for (int r = 0; r < 4; r++) {
        outv[r] += SB_s[r][tid];
        slotsOut[(size_t)(r0 + r) * 256 + tid] = outv[r];
    }
    // ---- next-iteration qproj: LN(out) with ln_sl, then @Wq ----
    if (emit_qp) {
        float s1[4], s2[4];
#pragma unroll
        for (int r = 0; r < 4; r++) { s1[r] = wred_sum(outv[r]); s2[r] = wred_sum(outv[r] * outv[r]); }
        if (lane == 0)
#pragma unroll
            for (int r = 0; r < 4; r++) { redA[wv][r] = s1[r]; redB[wv][r] = s2[r]; }
        __syncthreads();
        float gg = ln_sl_g[tid], bbv = ln_sl_b[tid];
#pragma unroll
        for (int r = 0; r < 4; r++) {
            float m  = (redA[0][r] + redA[1][r] + redA[2][r] + redA[3][r]) * (1.f / 256.f);
            float e2 = (redB[0][r] + redB[1][r] + redB[2][r] + redB[3][r]) * (1.f / 256.f);
            float rst = rsqrtf(e2 - m * m + LNEPS);
            M_s[r][tid] = (outv[r] - m) * rst * gg + bbv;
        }
        __syncthreads();
        float qacc[4] = {0.f, 0.f, 0.f, 0.f};
#pragma unroll 4
        for (int k = 0; k < 256; k++) {
            float wq = Wq[(size_t)k * 256 + tid];
#pragma unroll
            for (int r = 0; r < 4; r++) qacc[r] += M_s[r][k] * wq;
        }
#pragma unroll
        for (int r = 0; r < 4; r++) {
            int rg = r0 + r;
            int b = rg >> 3, q = rg & 7;
            qp[((size_t)(b * 4 + (tid >> 6)) * 8 + q) * 64 + (tid & 63)] = qacc[r];
        }
    }
}

// -------- host --------
extern "C" void kernel_launch(void* const* d_in, const int* in_sizes, int n_in,
                              void* d_out, int out_size, void* d_ws, size_t ws_size,
                              hipStream_t stream) {
    const float* inputs   = (const float*)d_in[0];
    const float* slots0   = (const float*)d_in[1];
    const float* ln_in_g  = (const float*)d_in[2];
    const float* ln_in_b  = (const float*)d_in[3];
    const float* ln_sl_g  = (const float*)d_in[4];
    const float* ln_sl_b  = (const float*)d_in[5];
    const float* ln_mlp_g = (const float*)d_in[6];
    const float* ln_mlp_b = (const float*)d_in[7];
    const float* Wq       = (const float*)d_in[8];
    const float* Wk       = (const float*)d_in[9];
    const float* Wv       = (const float*)d_in[10];
    const float* w_ih     = (const float*)d_in[11];
    const float* w_hh     = (const float*)d_in[12];
    const float* b_ih     = (const float*)d_in[13];
    const float* b_hh     = (const float*)d_in[14];
    const float* w1       = (const float*)d_in[15];
    const float* b1       = (const float*)d_in[16];
    const float* w2       = (const float*)d_in[17];
    const float* b2       = (const float*)d_in[18];

    float* out_slots = (float*)d_out;
    float* out_vis   = (float*)d_out + 64 * 8 * 256;

    char* p = (char*)d_ws;
    auto carve = [&](size_t bytes) {
        void* r = (void*)p;
        p += (bytes + 255) & ~(size_t)255;
        return r;
    };
    ushort_t* kv   = (ushort_t*)carve((size_t)65536 * 512 * 2);  // 64 MB
    ushort_t* Wt   = (ushort_t*)carve((size_t)512 * 256 * 2);
    float* w_ihT   = (float*)carve((size_t)256 * 768 * 4);
    float* w_hhT   = (float*)carve((size_t)256 * 768 * 4);
    float* meanb   = (float*)carve(65536 * 4);
    float* rstdb   = (float*)carve(65536 * 4);
    float* qp      = (float*)carve((size_t)64 * 2048 * 4);
    float* Upart   = (float*)carve((size_t)64 * 8 * 2048 * 4);   // 4 MB
    float* Cpart   = (float*)carve((size_t)64 * 8 * 32 * 4);
    float* updates = (float*)carve((size_t)512 * 256 * 4);
    float* slotsA  = (float*)carve((size_t)512 * 256 * 4);

    hipMemcpyAsync(slotsA, slots0, (size_t)512 * 256 * 4, hipMemcpyDeviceToDevice, stream);

    prepack_w_kernel<<<512, 256, 0, stream>>>(Wk, Wv, Wt);
    prepack_gru_kernel<<<dim3(12, 4, 2), 256, 0, stream>>>(w_ih, w_hh, w_ihT, w_hhT);
    rowstats_kernel<<<16384, 256, 0, stream>>>(inputs, meanb, rstdb);
    kvproj_mfma_kernel<<<1024, 512, 0, stream>>>(inputs, meanb, rstdb, ln_in_g, ln_in_b, Wt, kv);
    qproj_kernel<<<512, 256, 0, stream>>>(slotsA, ln_sl_g, ln_sl_b, Wq, qp);

    for (int it = 0; it < 3; ++it) {
        attn_fused_kernel<<<dim3(8, 64), 256, 0, stream>>>(kv, qp, Upart, Cpart, out_vis,
                                                           (it == 2) ? 1 : 0);
        updates_reduce_kernel<<<64, 256, 0, stream>>>(Upart, Cpart, updates);
        slot_fused_kernel<<<128, 256, 0, stream>>>(updates, slotsA, w_ihT, w_hhT, b_ih, b_hh,
                                                   ln_mlp_g, ln_mlp_b, w1, b1, w2, b2,
                                                   ln_sl_g, ln_sl_b, Wq,
                                                   (it == 2) ? out_slots : slotsA, qp,
                                                   (it < 2) ? 1 : 0);
    }
}

// Round 4
// 297.383 us; speedup vs baseline: 2.2442x; 1.9959x over previous
//
#include <hip/hip_runtime.h>
#include <hip/hip_bf16.h>
#include <math.h>

#define EPS_  1e-8f
#define LNEPS 1e-5f

typedef __attribute__((ext_vector_type(8))) short   short8;
typedef __attribute__((ext_vector_type(8))) __bf16  bf16x8;
typedef __attribute__((ext_vector_type(4))) float   f32x4;
typedef unsigned short ushort_t;

__device__ __forceinline__ float bf2f(unsigned int u) { return __uint_as_float(u << 16); }
__device__ __forceinline__ unsigned short f2bf(float f) {
    unsigned int u = __float_as_uint(f);
    u += 0x7fff + ((u >> 16) & 1);
    return (unsigned short)(u >> 16);
}
__device__ __forceinline__ f32x4 mfma_bf16(short8 a, short8 b, f32x4 c) {
    union U { short8 s; bf16x8 b; };
    U ua, ub; ua.s = a; ub.s = b;
    return __builtin_amdgcn_mfma_f32_16x16x32_bf16(ua.b, ub.b, c, 0, 0, 0);
}
__device__ __forceinline__ float wred_sum(float v) {
#pragma unroll
    for (int off = 32; off > 0; off >>= 1) v += __shfl_xor(v, off);
    return v;
}

// -------- prepack Wk/Wv -> Wt[n][k] bf16 (k pre-scaled 0.125) --------
__global__ __launch_bounds__(256) void prepack_w_kernel(const float* __restrict__ Wk,
                                                        const float* __restrict__ Wv,
                                                        ushort_t* __restrict__ Wt) {
    int n = blockIdx.x;
    int k = threadIdx.x;
    float v = (n < 256) ? Wk[(size_t)k * 256 + n] * 0.125f : Wv[(size_t)k * 256 + (n - 256)];
    Wt[(size_t)n * 256 + k] = f2bf(v);
}

// -------- prepack slot-chain weights to bf16 interleaved layouts --------
// sec0: wg[k][512][4]  slot t: (mh=t>>8) ih/hh, col c=t&255, elems {r,z,n,0}
// sec1: w1p[k4][512][4]  (k interleave 4)
// sec2: w2q[k4g(128)][256][4]   k = k4g*4+i
// sec3: Wqp[k4g(64)][256][4]    k = k4g*4+i
__global__ __launch_bounds__(512) void prepack_slotw_kernel(const float* __restrict__ w_ih,
                                                            const float* __restrict__ w_hh,
                                                            const float* __restrict__ w1,
                                                            const float* __restrict__ w2,
                                                            const float* __restrict__ Wq,
                                                            ushort_t* __restrict__ wg,
                                                            ushort_t* __restrict__ w1p,
                                                            ushort_t* __restrict__ w2q,
                                                            ushort_t* __restrict__ Wqp) {
    int t = threadIdx.x, bid = blockIdx.x, sec = blockIdx.y;
    if (sec == 0) {
        if (bid < 256) {
            int k = bid, mh = t >> 8, c = t & 255;
            const float* src = mh ? w_hh : w_ih;
            size_t o = ((size_t)k * 512 + t) * 4;
            wg[o + 0] = f2bf(src[(size_t)(0 * 256 + c) * 256 + k]);
            wg[o + 1] = f2bf(src[(size_t)(1 * 256 + c) * 256 + k]);
            wg[o + 2] = f2bf(src[(size_t)(2 * 256 + c) * 256 + k]);
            wg[o + 3] = 0;
        }
    } else if (sec == 1) {
        if (bid < 64) {
            size_t o = ((size_t)bid * 512 + t) * 4;
#pragma unroll
            for (int i = 0; i < 4; i++) w1p[o + i] = f2bf(w1[(size_t)(bid * 4 + i) * 512 + t]);
        }
    } else if (sec == 2) {
        if (bid < 64) {
            int k4g = bid * 2 + (t >> 8), c = t & 255;
            size_t o = ((size_t)k4g * 256 + c) * 4;
#pragma unroll
            for (int i = 0; i < 4; i++) w2q[o + i] = f2bf(w2[(size_t)(k4g * 4 + i) * 256 + c]);
        }
    } else {
        if (bid < 32) {
            int k4g = bid * 2 + (t >> 8), c = t & 255;
            size_t o = ((size_t)k4g * 256 + c) * 4;
#pragma unroll
            for (int i = 0; i < 4; i++) Wqp[o + i] = f2bf(Wq[(size_t)(k4g * 4 + i) * 256 + c]);
        }
    }
}

// -------- KV projection via MFMA, fused LN stats, persistent A-tile --------
// 1024 blocks x 512 threads. M-tile 64 rows, N=512 (all cols), BK=32 staged B.
__global__ __launch_bounds__(512) void kvproj_mfma_kernel(const float* __restrict__ in,
                                                          const float* __restrict__ g,
                                                          const float* __restrict__ bb,
                                                          const ushort_t* __restrict__ Wt,
                                                          ushort_t* __restrict__ kvout) {
    __shared__ __align__(16) ushort_t As[64 * 256];  // 32 KB, chunk-swizzled
    __shared__ __align__(16) ushort_t Bs[512 * 32];  // 32 KB
    const int tid = threadIdx.x;
    const int wv = tid >> 6, l = tid & 63;
    const int m0 = blockIdx.x * 64;
    const int row = tid >> 3, j = tid & 7;

    // phase 0: load full row slice, LN stats via 8-lane shfl, pack to As
    float4 xv[8], gv[8], bv[8];
    const float* rowp = in + (size_t)(m0 + row) * 256 + j * 32;
#pragma unroll
    for (int i = 0; i < 8; i++) {
        xv[i] = *(const float4*)(rowp + i * 4);
        gv[i] = *(const float4*)(g + j * 32 + i * 4);
        bv[i] = *(const float4*)(bb + j * 32 + i * 4);
    }
    float s1 = 0.f, s2 = 0.f;
#pragma unroll
    for (int i = 0; i < 8; i++) {
        s1 += xv[i].x + xv[i].y + xv[i].z + xv[i].w;
        s2 += xv[i].x * xv[i].x + xv[i].y * xv[i].y + xv[i].z * xv[i].z + xv[i].w * xv[i].w;
    }
#pragma unroll
    for (int off = 1; off < 8; off <<= 1) { s1 += __shfl_xor(s1, off); s2 += __shfl_xor(s2, off); }
    float mean = s1 * (1.0f / 256.0f);
    float rstd = rsqrtf(s2 * (1.0f / 256.0f) - mean * mean + LNEPS);
#pragma unroll
    for (int cc = 0; cc < 4; cc++) {
        short8 pk;
#pragma unroll
        for (int e = 0; e < 8; e++) {
            int i = cc * 8 + e;
            float x  = ((const float*)xv)[i];
            float gg = ((const float*)gv)[i];
            float b2v = ((const float*)bv)[i];
            pk[e] = (short)f2bf((x - mean) * rstd * gg + b2v);
        }
        int c = j * 4 + cc;  // global 16B chunk 0..31
        *(short8*)&As[row * 256 + ((c ^ (row & 7)) * 8)] = pk;
    }

    // B prefetch step 0
    short8 pw[4];
    const int bsw = (tid >> 1) & 3;
    {
        const ushort_t* src = Wt + (size_t)tid * 256;
#pragma unroll
        for (int c = 0; c < 4; c++) pw[c] = *(const short8*)(src + c * 8);
    }

    f32x4 zero = {0.f, 0.f, 0.f, 0.f};
    f32x4 acc[4][4];
#pragma unroll
    for (int i = 0; i < 4; i++)
#pragma unroll
        for (int jj = 0; jj < 4; jj++) acc[i][jj] = zero;

    for (int s = 0; s < 8; s++) {
#pragma unroll
        for (int c = 0; c < 4; c++)
            *(short8*)&Bs[tid * 32 + ((c ^ bsw) * 8)] = pw[c];
        if (s < 7) {
            const ushort_t* src = Wt + (size_t)tid * 256 + (s + 1) * 32;
#pragma unroll
            for (int c = 0; c < 4; c++) pw[c] = *(const short8*)(src + c * 8);
        }
        __syncthreads();
        const int kc = l >> 4;
        short8 af[4], bfr[4];
#pragma unroll
        for (int mi = 0; mi < 4; mi++) {
            int r2 = (l & 15) + mi * 16;
            int c = s * 4 + kc;
            af[mi] = *(const short8*)&As[r2 * 256 + ((c ^ (r2 & 7)) * 8)];
        }
#pragma unroll
        for (int ni = 0; ni < 4; ni++) {
            int n = wv * 64 + ni * 16 + (l & 15);
            bfr[ni] = *(const short8*)&Bs[n * 32 + ((kc ^ ((n >> 1) & 3)) * 8)];
        }
#pragma unroll
        for (int mi = 0; mi < 4; mi++)
#pragma unroll
            for (int ni = 0; ni < 4; ni++)
                acc[mi][ni] = mfma_bf16(af[mi], bfr[ni], acc[mi][ni]);
        __syncthreads();
    }
#pragma unroll
    for (int mi = 0; mi < 4; mi++)
#pragma unroll
        for (int ni = 0; ni < 4; ni++)
#pragma unroll
            for (int r = 0; r < 4; r++) {
                int rr2 = m0 + mi * 16 + (l >> 4) * 4 + r;
                int col = wv * 64 + ni * 16 + (l & 15);
                kvout[(size_t)rr2 * 512 + col] = f2bf(acc[mi][ni][r]);
            }
}

// -------- initial slot LN + q projection (once). grid 512 x 256 --------
__global__ __launch_bounds__(256) void qproj_kernel(const float* __restrict__ slots,
                                                    const float* __restrict__ g,
                                                    const float* __restrict__ bvec,
                                                    const float* __restrict__ Wq,
                                                    float* __restrict__ qp) {
    int row = blockIdx.x;
    int tid = threadIdx.x;
    __shared__ float s_s[256];
    __shared__ float red[8];
    float x = slots[(size_t)row * 256 + tid];
    float s1 = wred_sum(x);
    float s2 = wred_sum(x * x);
    if ((tid & 63) == 0) { red[tid >> 6] = s1; red[4 + (tid >> 6)] = s2; }
    __syncthreads();
    float m  = (red[0] + red[1] + red[2] + red[3]) * (1.0f / 256.0f);
    float e2 = (red[4] + red[5] + red[6] + red[7]) * (1.0f / 256.0f);
    float rst = rsqrtf(e2 - m * m + LNEPS);
    s_s[tid] = (x - m) * rst * g[tid] + bvec[tid];
    __syncthreads();
    float acc = 0.f;
#pragma unroll 4
    for (int d = 0; d < 256; d++) acc += s_s[d] * Wq[(size_t)d * 256 + tid];
    int b = row >> 3, q = row & 7;
    qp[((size_t)(b * 4 + (tid >> 6)) * 8 + q) * 64 + (tid & 63)] = acc;
}

// -------- fused attention: logits + joint softmax + colsum + unnormalized updates --------
__global__ __launch_bounds__(256) void attn_fused_kernel(const ushort_t* __restrict__ kv,
                                                         const float* __restrict__ qp,
                                                         float* __restrict__ Upart,
                                                         float* __restrict__ Cpart,
                                                         float* __restrict__ vis,
                                                         int write_vis) {
    int b = blockIdx.y;
    int chunk = blockIdx.x;
    int tid = threadIdx.x;
    __shared__ float qs[32 * 65];
    __shared__ float att[8][32];
    __shared__ float cred[4][32];
#pragma unroll
    for (int i = 0; i < 8; i++)
        qs[(tid >> 3) * 65 + (tid & 7) * 8 + i] = qp[(size_t)b * 2048 + tid * 8 + i];
    __syncthreads();

    const int lane = tid & 63;
    const int w = tid >> 6;
    const int hq = lane & 31;
    const int h_l = hq >> 3, q_l = hq & 7;
    const int tloc = w * 2 + (lane >> 5);
    const int h_u = tid >> 6, d_u = tid & 63;

    float creg = 0.f;
    float U[8] = {0.f, 0.f, 0.f, 0.f, 0.f, 0.f, 0.f, 0.f};
    const float* qrow = qs + hq * 65;

    for (int grp = 0; grp < 16; ++grp) {
        int n = chunk * 128 + grp * 8 + tloc;
        const ushort_t* krow = kv + (size_t)(b * 1024 + n) * 512 + h_l * 64;
        float acc = 0.f;
#pragma unroll
        for (int d8 = 0; d8 < 8; d8++) {
            short8 kk = *(const short8*)(krow + d8 * 8);
#pragma unroll
            for (int j = 0; j < 8; j++)
                acc += bf2f((unsigned short)kk[j]) * qrow[d8 * 8 + j];
        }
        float mx = acc;
#pragma unroll
        for (int off = 1; off < 32; off <<= 1) mx = fmaxf(mx, __shfl_xor(mx, off));
        float e = __expf(acc - mx);
        float sm = e;
#pragma unroll
        for (int off = 1; off < 32; off <<= 1) sm += __shfl_xor(sm, off);
        float attn = e / sm;
        float attE = attn + EPS_;
        att[tloc][hq] = attE;
        creg += attE;
        if (write_vis) {
            float vsum = attn;
            vsum += __shfl_xor(vsum, 8);
            vsum += __shfl_xor(vsum, 16);
            if (h_l == 0) vis[(size_t)(b * 8 + q_l) * 1024 + n] = vsum;
        }
        __syncthreads();
        const ushort_t* vrow = kv + (size_t)(b * 1024 + chunk * 128 + grp * 8) * 512 + 256 + h_u * 64 + d_u;
#pragma unroll
        for (int t2 = 0; t2 < 8; t2++) {
            float vv = bf2f(vrow[(size_t)t2 * 512]);
            float4 a01 = *(const float4*)&att[t2][h_u * 8];
            float4 a23 = *(const float4*)&att[t2][h_u * 8 + 4];
            U[0] += a01.x * vv; U[1] += a01.y * vv; U[2] += a01.z * vv; U[3] += a01.w * vv;
            U[4] += a23.x * vv; U[5] += a23.y * vv; U[6] += a23.z * vv; U[7] += a23.w * vv;
        }
        __syncthreads();
    }
    creg += __shfl_xor(creg, 32);
    if (lane < 32) cred[w][hq] = creg;
    __syncthreads();
    if (tid < 32)
        Cpart[(size_t)(b * 8 + chunk) * 32 + tid] =
            cred[0][tid] + cred[1][tid] + cred[2][tid] + cred[3][tid];
#pragma unroll
    for (int q = 0; q < 8; q++)
        Upart[(size_t)(b * 8 + chunk) * 2048 + q * 256 + h_u * 64 + d_u] = U[q];
}

// -------- fused slot update v2: reduce + GRU + gates + LN + MLP + residual + next qproj --------
// 256 blocks x 512 threads; 2 rows per block.
__global__ __launch_bounds__(512) void slot_fused_kernel(const float* __restrict__ Upart,
                                                         const float* __restrict__ Cpart,
                                                         const float* __restrict__ slotsIn,
                                                         const ushort_t* __restrict__ wg,
                                                         const float* __restrict__ b_ih,
                                                         const float* __restrict__ b_hh,
                                                         const float* __restrict__ ln_mlp_g,
                                                         const float* __restrict__ ln_mlp_b,
                                                         const ushort_t* __restrict__ w1p,
                                                         const float* __restrict__ b1,
                                                         const ushort_t* __restrict__ w2q,
                                                         const float* __restrict__ b2,
                                                         const float* __restrict__ ln_sl_g,
                                                         const float* __restrict__ ln_sl_b,
                                                         const ushort_t* __restrict__ Wqp,
                                                         float* __restrict__ slotsOut,
                                                         float* __restrict__ qp,
                                                         int emit_qp) {
    __shared__ float U_s[2][256], H_s[2][256];
    __shared__ float gsum[12][256];   // [(mh*3+g)*2+r][c]
    __shared__ float SB_s[2][256], M_s[2][256];
    __shared__ float hid_s[2][512];
    __shared__ float part_s[2][2][256];
    __shared__ float redA[8], redB[8];
    const int t = threadIdx.x;
    const int lane = t & 63, wvi = t >> 6;
    const int r0 = blockIdx.x * 2;
    const int rr = t >> 8;     // row role / mh role / kh role
    const int c = t & 255;

    // ---- updates reduce + normalize (was updates_reduce_kernel) ----
    {
        int rg = r0 + rr;
        int b = rg >> 3, q = rg & 7;
        int h = c >> 6;
        float C = 0.f, s = 0.f;
#pragma unroll
        for (int p2 = 0; p2 < 8; p2++) {
            C += Cpart[(size_t)(b * 8 + p2) * 32 + h * 8 + q];
            s += Upart[(size_t)(b * 8 + p2) * 2048 + q * 256 + c];
        }
        U_s[rr][c] = s / C;
        H_s[rr][c] = slotsIn[(size_t)rg * 256 + c];
    }
    __syncthreads();

    // ---- GRU GEMV: thread = (mh=rr, col=c), both rows ----
    {
        const float* bias = rr ? b_hh : b_ih;
        float ar0 = bias[c], az0 = bias[256 + c], an0 = bias[512 + c];
        float ar1 = ar0, az1 = az0, an1 = an0;
        const float (*act)[256] = rr ? H_s : U_s;
        const ushort_t* wp = wg + (size_t)t * 4;
#pragma unroll 8
        for (int k = 0; k < 256; k++) {
            uint2 wv2 = *(const uint2*)(wp + (size_t)k * 2048);
            float w0 = bf2f(wv2.x & 0xffffu);
            float w1_ = bf2f(wv2.x >> 16);
            float w2_ = bf2f(wv2.y & 0xffffu);
            float a0 = act[0][k], a1 = act[1][k];
            ar0 += a0 * w0; az0 += a0 * w1_; an0 += a0 * w2_;
            ar1 += a1 * w0; az1 += a1 * w1_; an1 += a1 * w2_;
        }
        gsum[rr * 6 + 0][c] = ar0; gsum[rr * 6 + 1][c] = ar1;
        gsum[rr * 6 + 2][c] = az0; gsum[rr * 6 + 3][c] = az1;
        gsum[rr * 6 + 4][c] = an0; gsum[rr * 6 + 5][c] = an1;
    }
    __syncthreads();

    // ---- gates: thread = (row=rr, col=c) ----
    float sb;
    {
        float xr = gsum[0 + rr][c], xz = gsum[2 + rr][c], xn = gsum[4 + rr][c];
        float hr = gsum[6 + rr][c], hz = gsum[8 + rr][c], hn = gsum[10 + rr][c];
        float rg_ = 1.f / (1.f + __expf(-(xr + hr)));
        float z   = 1.f / (1.f + __expf(-(xz + hz)));
        float nn  = tanhf(xn + rg_ * hn);
        sb = (1.f - z) * nn + z * H_s[rr][c];
        SB_s[rr][c] = sb;
    }
    // ---- LN(mlp) ----
    {
        float s1 = wred_sum(sb), s2 = wred_sum(sb * sb);
        if (lane == 0) { redA[wvi] = s1; redB[wvi] = s2; }
        __syncthreads();
        int base = rr * 4;
        float m  = (redA[base] + redA[base + 1] + redA[base + 2] + redA[base + 3]) * (1.f / 256.f);
        float e2 = (redB[base] + redB[base + 1] + redB[base + 2] + redB[base + 3]) * (1.f / 256.f);
        float rst = rsqrtf(e2 - m * m + LNEPS);
        M_s[rr][c] = (sb - m) * rst * ln_mlp_g[c] + ln_mlp_b[c];
    }
    __syncthreads();

    // ---- MLP1: thread = col j = t (0..511), both rows ----
    {
        float bb1 = b1[t];
        float h10 = bb1, h11 = bb1;
        const ushort_t* wp = w1p + (size_t)t * 4;
#pragma unroll 4
        for (int k4 = 0; k4 < 64; k4++) {
            uint2 wv2 = *(const uint2*)(wp + (size_t)k4 * 2048);
            float w[4] = {bf2f(wv2.x & 0xffffu), bf2f(wv2.x >> 16),
                          bf2f(wv2.y & 0xffffu), bf2f(wv2.y >> 16)};
#pragma unroll
            for (int i = 0; i < 4; i++) {
                int k = k4 * 4 + i;
                h10 += M_s[0][k] * w[i];
                h11 += M_s[1][k] * w[i];
            }
        }
        hid_s[0][t] = fmaxf(h10, 0.f);
        hid_s[1][t] = fmaxf(h11, 0.f);
    }
    __syncthreads();

    // ---- MLP2: thread = (kh=rr, col=c), both rows, half the k range ----
    {
        float p0 = 0.f, p1 = 0.f;
        const ushort_t* wp = w2q + ((size_t)rr * 64 * 256 + c) * 4;
#pragma unroll 4
        for (int k4 = 0; k4 < 64; k4++) {
            uint2 wv2 = *(const uint2*)(wp + (size_t)k4 * 1024);
            float w[4] = {bf2f(wv2.x & 0xffffu), bf2f(wv2.x >> 16),
                          bf2f(wv2.y & 0xffffu), bf2f(wv2.y >> 16)};
#pragma unroll
            for (int i = 0; i < 4; i++) {
                int k = rr * 256 + k4 * 4 + i;
                p0 += hid_s[0][k] * w[i];
                p1 += hid_s[1][k] * w[i];
            }
        }
        part_s[rr][0][c] = p0;
        part_s[rr][1][c] = p1;
    }
    __syncthreads();

    // ---- combine + residual + store ----
    float outv = part_s[0][rr][c] + part_s[1][rr][c] + b2[c] + SB_s[rr][c];
    slotsOut[(size_t)(r0 + rr) * 256 + c] = outv;

    // ---- optional: LN(sl) + qproj for next iteration ----
    if (emit_qp) {
        float s1 = wred_sum(outv), s2 = wred_sum(outv * outv);
        __syncthreads();
        if (lane == 0) { redA[wvi] = s1; redB[wvi] = s2; }
        __syncthreads();
        int base = rr * 4;
        float m  = (redA[base] + redA[base + 1] + redA[base + 2] + redA[base + 3]) * (1.f / 256.f);
        float e2 = (redB[base] + redB[base + 1] + redB[base + 2] + redB[base + 3]) * (1.f / 256.f);
        float rst = rsqrtf(e2 - m * m + LNEPS);
        M_s[rr][c] = (outv - m) * rst * ln_sl_g[c] + ln_sl_b[c];
        __syncthreads();
        float p0 = 0.f, p1 = 0.f;
        const ushort_t* wp = Wqp + ((size_t)rr * 32 * 256 + c) * 4;
#pragma unroll 4
        for (int k4 = 0; k4 < 32; k4++) {
            uint2 wv2 = *(const uint2*)(wp + (size_t)k4 * 1024);
            float w[4] = {bf2f(wv2.x & 0xffffu), bf2f(wv2.x >> 16),
                          bf2f(wv2.y & 0xffffu), bf2f(wv2.y >> 16)};
#pragma unroll
            for (int i = 0; i < 4; i++) {
                int k = rr * 128 + k4 * 4 + i;
                p0 += M_s[0][k] * w[i];
                p1 += M_s[1][k] * w[i];
            }
        }
        part_s[rr][0][c] = p0;
        part_s[rr][1][c] = p1;
        __syncthreads();
        float qv = part_s[0][rr][c] + part_s[1][rr][c];
        int rg = r0 + rr, b = rg >> 3, q = rg & 7;
        qp[(size_t)b * 2048 + (c >> 6) * 512 + q * 64 + (c & 63)] = qv;
    }
}

// -------- host --------
extern "C" void kernel_launch(void* const* d_in, const int* in_sizes, int n_in,
                              void* d_out, int out_size, void* d_ws, size_t ws_size,
                              hipStream_t stream) {
    const float* inputs   = (const float*)d_in[0];
    const float* slots0   = (const float*)d_in[1];
    const float* ln_in_g  = (const float*)d_in[2];
    const float* ln_in_b  = (const float*)d_in[3];
    const float* ln_sl_g  = (const float*)d_in[4];
    const float* ln_sl_b  = (const float*)d_in[5];
    const float* ln_mlp_g = (const float*)d_in[6];
    const float* ln_mlp_b = (const float*)d_in[7];
    const float* Wq       = (const float*)d_in[8];
    const float* Wk       = (const float*)d_in[9];
    const float* Wv       = (const float*)d_in[10];
    const float* w_ih     = (const float*)d_in[11];
    const float* w_hh     = (const float*)d_in[12];
    const float* b_ih     = (const float*)d_in[13];
    const float* b_hh     = (const float*)d_in[14];
    const float* w1       = (const float*)d_in[15];
    const float* b1       = (const float*)d_in[16];
    const float* w2       = (const float*)d_in[17];
    const float* b2       = (const float*)d_in[18];

    float* out_slots = (float*)d_out;
    float* out_vis   = (float*)d_out + 64 * 8 * 256;

    char* p = (char*)d_ws;
    auto carve = [&](size_t bytes) {
        void* r = (void*)p;
        p += (bytes + 255) & ~(size_t)255;
        return r;
    };
    ushort_t* kv   = (ushort_t*)carve((size_t)65536 * 512 * 2);   // 64 MB
    ushort_t* Wt   = (ushort_t*)carve((size_t)512 * 256 * 2);
    ushort_t* wg   = (ushort_t*)carve((size_t)256 * 512 * 4 * 2); // 1 MB
    ushort_t* w1p  = (ushort_t*)carve((size_t)64 * 512 * 4 * 2);
    ushort_t* w2q  = (ushort_t*)carve((size_t)128 * 256 * 4 * 2);
    ushort_t* Wqp  = (ushort_t*)carve((size_t)64 * 256 * 4 * 2);
    float* qp      = (float*)carve((size_t)64 * 2048 * 4);
    float* Upart   = (float*)carve((size_t)64 * 8 * 2048 * 4);    // 4 MB
    float* Cpart   = (float*)carve((size_t)64 * 8 * 32 * 4);
    float* slotsA  = (float*)carve((size_t)512 * 256 * 4);

    prepack_w_kernel<<<512, 256, 0, stream>>>(Wk, Wv, Wt);
    prepack_slotw_kernel<<<dim3(256, 4), 512, 0, stream>>>(w_ih, w_hh, w1, w2, Wq,
                                                           wg, w1p, w2q, Wqp);
    kvproj_mfma_kernel<<<1024, 512, 0, stream>>>(inputs, ln_in_g, ln_in_b, Wt, kv);
    qproj_kernel<<<512, 256, 0, stream>>>(slots0, ln_sl_g, ln_sl_b, Wq, qp);

    for (int it = 0; it < 3; ++it) {
        attn_fused_kernel<<<dim3(8, 64), 256, 0, stream>>>(kv, qp, Upart, Cpart, out_vis,
                                                           (it == 2) ? 1 : 0);
        slot_fused_kernel<<<256, 512, 0, stream>>>(
            Upart, Cpart, (it == 0) ? slots0 : slotsA,
            wg, b_ih, b_hh, ln_mlp_g, ln_mlp_b, w1p, b1, w2q, b2,
            ln_sl_g, ln_sl_b, Wqp,
            (it == 2) ? out_slots : slotsA, qp, (it < 2) ? 1 : 0);
    }
}